// Round 12
// baseline (1166.036 us; speedup 1.0000x reference)
//
#include <hip/hip_runtime.h>
#include <hip/hip_bf16.h>
#include <math.h>

#define NBLK 6
#define NH 4
#define CCH 192
#define BB 2
#define SS 64
#define LL 256
#define DH 48
#define NP (BB*SS*LL)            // 32768 pixels
#define BUF ((size_t)NP*CCH)

typedef __attribute__((ext_vector_type(8))) short short8;
typedef __attribute__((ext_vector_type(4))) float float4v;
typedef __attribute__((ext_vector_type(2))) unsigned int uintx2;

__device__ __forceinline__ unsigned short f2b(float f) {
    union { float f; unsigned int u; } v; v.f = f;
    unsigned int r = v.u + 0x7FFF + ((v.u >> 16) & 1);
    return (unsigned short)(r >> 16);
}
__device__ __forceinline__ float b2f(unsigned short u) {
    union { unsigned int u; float f; } v; v.u = ((unsigned int)u) << 16;
    return v.f;
}
// packed f32x2 -> bf16x2 (RNE)
__device__ __forceinline__ unsigned int cvt_pk_bf16(float lo, float hi) {
    unsigned int r;
    asm("v_cvt_pk_bf16_f32 %0, %1, %2" : "=v"(r) : "v"(lo), "v"(hi));
    return r;
}
__device__ __forceinline__ void st2u(unsigned short* p0, unsigned short* p1, float a, float b) {
    unsigned int u = cvt_pk_bf16(a, b);
    *p0 = (unsigned short)u;
    *p1 = (unsigned short)(u >> 16);
}
__device__ __forceinline__ void xf_unpack(uintx2 u, float* f) {
    union { unsigned int x; float ff; } t;
    t.x = u[0] << 16;          f[0] = t.ff;
    t.x = u[0] & 0xffff0000u;  f[1] = t.ff;
    t.x = u[1] << 16;          f[2] = t.ff;
    t.x = u[1] & 0xffff0000u;  f[3] = t.ff;
}
// exact-GELU via branch-free A&S 7.1.26 erf (|err| <= 1.5e-7)
__device__ __forceinline__ float gelu_f(float v) {
    float z = v * 0.7071067811865475f;
    float a = fabsf(z);
    float t = __builtin_amdgcn_rcpf(fmaf(0.3275911f, a, 1.0f));
    float p = fmaf(t, 1.061405429f, -1.453152027f);
    p = fmaf(t, p, 1.421413741f);
    p = fmaf(t, p, -0.284496736f);
    p = fmaf(t, p, 0.254829592f);
    p *= t;
    float e = __expf(-a * a);
    float er = fmaf(-p, e, 1.0f);
    er = __builtin_copysignf(er, z);
    return 0.5f * v * (1.0f + er);
}
__device__ __forceinline__ void async_lds16(const void* g, void* l) {
    __builtin_amdgcn_global_load_lds(
        (const __attribute__((address_space(1))) unsigned int*)g,
        (__attribute__((address_space(3))) unsigned int*)l, 16, 0, 0);
}

// fragment-major residual layout: element (p,c) lives at ((p>>4)*192 + c)*16 + (p&15)
#define XF(p16, c) (((size_t)(p16) * 192 + (c)) << 4)

// ---------- weight prep: fragment-major swizzle ----------
template<int N, int K>
__global__ void swz_conv(const float* __restrict__ src, unsigned short* __restrict__ dst, int layers) {
    int s = blockIdx.x * 256 + threadIdx.x;
    if (s >= layers * N * K) return;
    int li = s / (N * K);
    int t = s - li * (N * K);
    constexpr int KC = K / 32;
    int chunk = t >> 9, c = t & 511;
    int g = chunk / KC, sk = chunk - g * KC;
    int lane = c >> 3, ko = c & 7;
    int n = g * 16 + (lane & 15), k = sk * 32 + (lane >> 4) * 8 + ko;
    dst[s] = f2b(src[(size_t)li * N * K + (size_t)n * K + k]);
}
__global__ void wqkv_swz(const float* __restrict__ wq, const float* __restrict__ wk,
                         const float* __restrict__ wv, unsigned short* __restrict__ d) {
    int s = blockIdx.x * 256 + threadIdx.x;          // 12*576*192
    int wi = s / (576 * 192);
    int t = s - wi * 576 * 192;
    int chunk = t >> 9, c = t & 511;
    int g = chunk / 6, sk = chunk - g * 6;
    int lane = c >> 3, ko = c & 7;
    int n = g * 16 + (lane & 15), k = sk * 32 + (lane >> 4) * 8 + ko;
    int sg = n / 192, row = n - sg * 192;
    const float* src = (sg == 0) ? wq : (sg == 1) ? wk : wv;
    d[s] = f2b(src[(size_t)wi * 192 * 192 + (size_t)row * 192 + k]);
}
__global__ void bqkv_concat(const float* __restrict__ bq, const float* __restrict__ bk,
                            const float* __restrict__ bv, float* __restrict__ d) {
    int idx = blockIdx.x * 256 + threadIdx.x;        // 12*576
    if (idx >= NBLK * 2 * 576) return;
    int wi = idx / 576, n = idx - (idx / 576) * 576;
    int sg = n / 192, row = n - sg * 192;
    const float* src = (sg == 0) ? bq : (sg == 1) ? bk : bv;
    d[idx] = src[wi * CCH + row];
}

__global__ void gather_kernel(const int* __restrict__ tokens, const float* __restrict__ emb,
                              unsigned short* __restrict__ Eg) {
    int idx = blockIdx.x * 256 + threadIdx.x;   // NP*64
    int p = idx >> 6, c = idx & 63;
    Eg[idx] = f2b(emb[tokens[p] * 64 + c]);
}

// rotary + first LayerNorm fused; X stored bf16 fragment-major (storage only — math fp32)
__global__ __launch_bounds__(256) void rotary_ln_kernel(const float* __restrict__ Xt,
                                                        unsigned short* __restrict__ X,
                                                        unsigned short* __restrict__ Hn,
                                                        const float* __restrict__ g, const float* __restrict__ b) {
    int wave = threadIdx.x >> 6;
    int lane = threadIdx.x & 63;
    int p = blockIdx.x * 4 + wave;
    int l = p & (LL - 1);
    const float* xp = Xt + (size_t)p * CCH;
    float v[3];
    #pragma unroll
    for (int i = 0; i < 3; ++i) {
        int c = lane + i * 64;
        int j = c % 96;
        float inv = expf((float)(2 * j) * (-9.210340371976184f / 192.0f));
        float ang = (float)l * inv;
        float part = (c < 96) ? -xp[c + 96] : xp[c - 96];
        v[i] = xp[c] * cosf(ang) + part * sinf(ang);
    }
    float s = v[0] + v[1] + v[2];
    float qq = v[0] * v[0] + v[1] * v[1] + v[2] * v[2];
    #pragma unroll
    for (int off = 32; off; off >>= 1) {
        s += __shfl_xor(s, off, 64);
        qq += __shfl_xor(qq, off, 64);
    }
    float mean = s * (1.0f / 192.0f);
    float var = qq * (1.0f / 192.0f) - mean * mean;
    float r = rsqrtf(var + 1e-5f);
    unsigned short* hp = Hn + (size_t)p * CCH;
    const int p16 = p >> 4, pr = p & 15;
    #pragma unroll
    for (int i = 0; i < 3; ++i) {
        int c = lane + i * 64;
        X[XF(p16, c) + pr] = f2b(v[i]);
        hp[c] = f2b((v[i] - mean) * r * g[c] + b[c]);
    }
}

// ---------------- bf16 MFMA GEMM (pre-loop only: proj, block-0 QKV) ----------------
template<int MT, int EPI>
__global__ __launch_bounds__(256, (MT == 128) ? 3 : 4)
void mm192(const unsigned short* __restrict__ A, const unsigned short* __restrict__ Wsw,
           const float* __restrict__ bias,
           unsigned short* __restrict__ O0, unsigned short* __restrict__ O1,
           unsigned short* __restrict__ O2,
           float* __restrict__ Of,
           int M, int N, int K) {
    constexpr int NI = MT / 32;
    __shared__ __align__(16) unsigned char lds[(MT == 128) ? 51200 : 28672];
    const int tid = threadIdx.x;
    const int lane = tid & 63;
    const int w = tid >> 6;
    const int wm = w >> 1, wn = w & 1;
    const int m0 = blockIdx.y * MT;
    const int g0 = blockIdx.x * 12;
    const int q = lane >> 4;
    const int q8 = q << 3;
    const int r15 = lane & 15;
    const int KC = K >> 5;

    for (int c = w; c < (MT / 16) * KC; c += 4) {
        int g = c / KC, sk = c - g * KC;
        async_lds16(A + (size_t)(m0 + g * 16 + r15) * K + sk * 32 + q8, lds + c * 1024);
    }

    float4v acc[NI][6];
    #pragma unroll
    for (int i = 0; i < NI; ++i)
        #pragma unroll
        for (int j = 0; j < 6; ++j)
            acc[i][j] = (float4v){0.f, 0.f, 0.f, 0.f};

    __syncthreads();

    for (int sk = 0; sk < KC; ++sk) {
        short8 af[NI], wf[6];
        #pragma unroll
        for (int j = 0; j < 6; ++j)
            wf[j] = *(const short8*)(Wsw + (((size_t)(g0 + wn * 6 + j) * KC + sk) << 9) + lane * 8);
        #pragma unroll
        for (int i = 0; i < NI; ++i)
            af[i] = *(const short8*)(lds + (((wm * NI + i) * KC + sk) << 10) + lane * 16);
        #pragma unroll
        for (int i = 0; i < NI; ++i)
            #pragma unroll
            for (int j = 0; j < 6; ++j)
                acc[i][j] = __builtin_amdgcn_mfma_f32_16x16x32_bf16(af[i], wf[j], acc[i][j], 0, 0, 0);
    }

    const int nb = blockIdx.x * 192 + wn * 96 + r15;
    const int mb = m0 + wm * (MT / 2) + q * 4;

    if (EPI == 0) {
        const int bx = blockIdx.x;
        unsigned short* dst = (bx == 0) ? O0 : (bx == 1) ? O1 : O2;
        #pragma unroll
        for (int j = 0; j < 6; ++j) {
            int n = nb + j * 16;                      // global 576-wide col (bias)
            int col = wn * 96 + j * 16 + r15;         // local 192-wide col (store)
            float bv = bias[n];
            #pragma unroll
            for (int i = 0; i < NI; ++i) {
                int mrow = wm * (MT / 2) + i * 16 + q * 4;
                #pragma unroll
                for (int r = 0; r < 4; ++r) {
                    float v = acc[i][j][r] + bv;
                    if (bx < 2) v = (v > 0.f) ? v + 1.f : __expf(v);
                    if (bx == 0) v *= 0.14433756729740643f;
                    dst[(size_t)(m0 + mrow + r) * 192 + col] = f2b(v);
                }
            }
        }
    } else {
        #pragma unroll
        for (int j = 0; j < 6; ++j) {
            int n = nb + j * 16;
            float bv = bias[n];
            #pragma unroll
            for (int i = 0; i < NI; ++i) {
                int mrow = mb + i * 16;
                #pragma unroll
                for (int r = 0; r < 4; ++r)
                    Of[(size_t)(mrow + r) * N + n] = acc[i][j][r] + bv;
            }
        }
    }
}

// ======== fused per-pixel GEMM chains ========

// ---- WO + residual + LN + QKV (32 rows/block, 256 threads — R3 config, best measured) ----
// LDS (25600 B): Lo [0,12288) staging | stats [12288,13312) | Ap [13312,25600)
__global__ __launch_bounds__(256, 4)
void wo_qkv(const unsigned short* __restrict__ Ho,
            const unsigned short* __restrict__ WOs, const float* __restrict__ BO,
            unsigned short* __restrict__ Xres,
            const float* __restrict__ lng, const float* __restrict__ lnb,
            const unsigned short* __restrict__ QKVs, const float* __restrict__ bqkv,
            unsigned short* __restrict__ Qb, unsigned short* __restrict__ Kb,
            unsigned short* __restrict__ Vb) {
    __shared__ __align__(16) unsigned char lds[25600];
    unsigned char* Lo = lds;
    float* lsum = (float*)(lds + 12288);     // [32][4]
    float* lsq  = lsum + 128;
    unsigned char* Ap = lds + 13312;
    const int tid = threadIdx.x;
    const int lane = tid & 63;
    const int w = tid >> 6;                  // 0..3
    const int m0 = blockIdx.x * 32;
    const int q = lane >> 4, q8 = q << 3, r15 = lane & 15;
    const int nb = w * 48 + r15;

    #pragma unroll
    for (int it = 0; it < 3; ++it) {
        int c = it * 4 + w;                  // 0..11
        int g = c / 6, sk = c - g * 6;
        async_lds16(Ho + (size_t)(m0 + g * 16 + r15) * 192 + sk * 32 + q8, Lo + c * 1024);
    }
    __syncthreads();

    float4v acc[2][3];
    #pragma unroll
    for (int i = 0; i < 2; ++i)
        #pragma unroll
        for (int j = 0; j < 3; ++j)
            acc[i][j] = (float4v){0.f, 0.f, 0.f, 0.f};
    #pragma unroll
    for (int kk = 0; kk < 6; ++kk) {
        short8 af[2], wf[3];
        #pragma unroll
        for (int j = 0; j < 3; ++j)
            wf[j] = *(const short8*)(WOs + (((size_t)(w * 3 + j) * 6 + kk) << 9) + lane * 8);
        #pragma unroll
        for (int i = 0; i < 2; ++i)
            af[i] = *(const short8*)(Lo + ((i * 6 + kk) << 10) + lane * 16);
        #pragma unroll
        for (int i = 0; i < 2; ++i)
            #pragma unroll
            for (int j = 0; j < 3; ++j)
                acc[i][j] = __builtin_amdgcn_mfma_f32_16x16x32_bf16(af[i], wf[j], acc[i][j], 0, 0, 0);
    }

    // residual (vector 8B read-modify-write, fragment-major X), LN stats
    #pragma unroll
    for (int j = 0; j < 3; ++j) {
        int n = nb + j * 16;
        float bv = BO[n];
        #pragma unroll
        for (int i = 0; i < 2; ++i) {
            unsigned short* xp = Xres + XF(blockIdx.x * 2 + i, n) + q * 4;
            uintx2 u = *(const uintx2*)xp;
            float f[4]; xf_unpack(u, f);
            #pragma unroll
            for (int r = 0; r < 4; ++r) acc[i][j][r] += bv + f[r];
            uintx2 o;
            o[0] = cvt_pk_bf16(acc[i][j][0], acc[i][j][1]);
            o[1] = cvt_pk_bf16(acc[i][j][2], acc[i][j][3]);
            *(uintx2*)xp = o;
        }
    }
    #pragma unroll
    for (int i = 0; i < 2; ++i)
        #pragma unroll
        for (int r = 0; r < 4; ++r) {
            float s1 = acc[i][0][r] + acc[i][1][r] + acc[i][2][r];
            float s2 = acc[i][0][r] * acc[i][0][r] + acc[i][1][r] * acc[i][1][r] + acc[i][2][r] * acc[i][2][r];
            #pragma unroll
            for (int off = 1; off < 16; off <<= 1) {
                s1 += __shfl_xor(s1, off, 64);
                s2 += __shfl_xor(s2, off, 64);
            }
            if (r15 == 0) {
                int rl = i * 16 + q * 4 + r;
                lsum[rl * 4 + w] = s1;
                lsq[rl * 4 + w] = s2;
            }
        }
    __syncthreads();
    #pragma unroll
    for (int i = 0; i < 2; ++i) {
        float mean[4], rstd[4];
        #pragma unroll
        for (int r = 0; r < 4; ++r) {
            int rl4 = (i * 16 + q * 4 + r) * 4;
            float s  = lsum[rl4] + lsum[rl4 + 1] + lsum[rl4 + 2] + lsum[rl4 + 3];
            float ss = lsq[rl4] + lsq[rl4 + 1] + lsq[rl4 + 2] + lsq[rl4 + 3];
            float m = s * (1.0f / 192.0f);
            mean[r] = m;
            rstd[r] = rsqrtf(ss * (1.0f / 192.0f) - m * m + 1e-5f);
        }
        #pragma unroll
        for (int j = 0; j < 3; ++j) {
            int h = nb + j * 16;
            float gg = lng[h], bb = lnb[h];
            unsigned short* ap = (unsigned short*)Ap + (i * 6 + (h >> 5)) * 512
                               + ((h >> 3) & 3) * 128 + (h & 7) + q * 32;
            float v0 = (acc[i][j][0] - mean[0]) * rstd[0] * gg + bb;
            float v1 = (acc[i][j][1] - mean[1]) * rstd[1] * gg + bb;
            float v2 = (acc[i][j][2] - mean[2]) * rstd[2] * gg + bb;
            float v3 = (acc[i][j][3] - mean[3]) * rstd[3] * gg + bb;
            st2u(ap, ap + 8, v0, v1);
            st2u(ap + 16, ap + 24, v2, v3);
        }
    }
    __syncthreads();

    // QKV: 3 segments, direct global stores
    for (int seg = 0; seg < 3; ++seg) {
        float4v a2[2][3];
        #pragma unroll
        for (int i = 0; i < 2; ++i)
            #pragma unroll
            for (int j = 0; j < 3; ++j)
                a2[i][j] = (float4v){0.f, 0.f, 0.f, 0.f};
        #pragma unroll
        for (int kk = 0; kk < 6; ++kk) {
            short8 af[2], wf[3];
            #pragma unroll
            for (int j = 0; j < 3; ++j)
                wf[j] = *(const short8*)(QKVs + (((size_t)(seg * 12 + w * 3 + j) * 6 + kk) << 9) + lane * 8);
            #pragma unroll
            for (int i = 0; i < 2; ++i)
                af[i] = *(const short8*)(Ap + ((i * 6 + kk) << 10) + lane * 16);
            #pragma unroll
            for (int i = 0; i < 2; ++i)
                #pragma unroll
                for (int j = 0; j < 3; ++j)
                    a2[i][j] = __builtin_amdgcn_mfma_f32_16x16x32_bf16(af[i], wf[j], a2[i][j], 0, 0, 0);
        }
        unsigned short* dst = (seg == 0) ? Qb : (seg == 1) ? Kb : Vb;
        #pragma unroll
        for (int j = 0; j < 3; ++j) {
            int n = nb + j * 16;
            float bv = bqkv[seg * 192 + n];
            #pragma unroll
            for (int i = 0; i < 2; ++i) {
                int mrow = m0 + i * 16 + q * 4;
                #pragma unroll
                for (int r = 0; r < 4; ++r) {
                    float x = a2[i][j][r] + bv;
                    if (seg < 2) x = (x > 0.f) ? x + 1.f : __expf(x);
                    if (seg == 0) x *= 0.14433756729740643f;
                    dst[(size_t)(mrow + r) * 192 + n] = f2b(x);
                }
            }
        }
    }
}

// ---- WO + residual(reg) + LN + FFN + residual + LN + next-QKV ----
// 64 rows/block, 384 threads (6 waves x 32-col slices): keeps R6's halved weight
// traffic (each col covered once/block) while raising occupancy 8->12 waves/CU.
// LDS (52224 B): Lo [0,24576) staging/hidden | stats [24576,27648) [64][6]x2 | Ap [27648,52224)
template<bool LASTB>
__global__ __launch_bounds__(384, 3)
void wo_ffn_qkv(const unsigned short* __restrict__ Ho,
                const unsigned short* __restrict__ WOs, const float* __restrict__ BO,
                unsigned short* __restrict__ Xres,
                const float* __restrict__ ln1g, const float* __restrict__ ln1b,
                const unsigned short* __restrict__ W1s, const float* __restrict__ B1,
                const unsigned short* __restrict__ W2s, const float* __restrict__ B2,
                const float* __restrict__ ln2g, const float* __restrict__ ln2b,
                const unsigned short* __restrict__ QKVs, const float* __restrict__ bqkv,
                unsigned short* __restrict__ Qb, unsigned short* __restrict__ Kb,
                unsigned short* __restrict__ Vb) {
    __shared__ __align__(16) unsigned char lds[52224];
    unsigned char* Lo = lds;                 // staging, then FFN hidden
    float* lsum = (float*)(lds + 24576);     // [64][6]
    float* lsq  = lsum + 384;
    unsigned char* Ap = lds + 27648;
    const int tid = threadIdx.x;
    const int lane = tid & 63;
    const int w = tid >> 6;                  // 0..5
    const int m0 = blockIdx.x * 64;
    const int q = lane >> 4, q8 = q << 3, r15 = lane & 15;
    const int nb = w * 32 + r15;             // 32-col slice

    #pragma unroll
    for (int it = 0; it < 4; ++it) {
        int c = it * 6 + w;                  // 0..23
        int g = c / 6, sk = c - g * 6;
        async_lds16(Ho + (size_t)(m0 + g * 16 + r15) * 192 + sk * 32 + q8, Lo + c * 1024);
    }
    __syncthreads();

    float4v xres[4][2];
    #pragma unroll
    for (int i = 0; i < 4; ++i)
        #pragma unroll
        for (int j = 0; j < 2; ++j)
            xres[i][j] = (float4v){0.f, 0.f, 0.f, 0.f};
    #pragma unroll
    for (int kk = 0; kk < 6; ++kk) {
        short8 af[4], wf[2];
        #pragma unroll
        for (int j = 0; j < 2; ++j)
            wf[j] = *(const short8*)(WOs + (((size_t)(w * 2 + j) * 6 + kk) << 9) + lane * 8);
        #pragma unroll
        for (int i = 0; i < 4; ++i)
            af[i] = *(const short8*)(Lo + ((i * 6 + kk) << 10) + lane * 16);
        #pragma unroll
        for (int i = 0; i < 4; ++i)
            #pragma unroll
            for (int j = 0; j < 2; ++j)
                xres[i][j] = __builtin_amdgcn_mfma_f32_16x16x32_bf16(af[i], wf[j], xres[i][j], 0, 0, 0);
    }
    // residual into registers (vector 8B read; write deferred to after FFN)
    #pragma unroll
    for (int j = 0; j < 2; ++j) {
        int n = nb + j * 16;
        float bv = BO[n];
        #pragma unroll
        for (int i = 0; i < 4; ++i) {
            const unsigned short* xp = Xres + XF(blockIdx.x * 4 + i, n) + q * 4;
            uintx2 u = *(const uintx2*)xp;
            float f[4]; xf_unpack(u, f);
            #pragma unroll
            for (int r = 0; r < 4; ++r) xres[i][j][r] += bv + f[r];
        }
    }
    // LN1 stats + scatter A'
    #pragma unroll
    for (int i = 0; i < 4; ++i)
        #pragma unroll
        for (int r = 0; r < 4; ++r) {
            float s1 = xres[i][0][r] + xres[i][1][r];
            float s2 = xres[i][0][r] * xres[i][0][r] + xres[i][1][r] * xres[i][1][r];
            #pragma unroll
            for (int off = 1; off < 16; off <<= 1) {
                s1 += __shfl_xor(s1, off, 64);
                s2 += __shfl_xor(s2, off, 64);
            }
            if (r15 == 0) {
                int rl = i * 16 + q * 4 + r;
                lsum[rl * 6 + w] = s1;
                lsq[rl * 6 + w] = s2;
            }
        }
    __syncthreads();
    #pragma unroll
    for (int i = 0; i < 4; ++i) {
        float mean[4], rstd[4];
        #pragma unroll
        for (int r = 0; r < 4; ++r) {
            int rl6 = (i * 16 + q * 4 + r) * 6;
            float s  = lsum[rl6] + lsum[rl6 + 1] + lsum[rl6 + 2] + lsum[rl6 + 3] + lsum[rl6 + 4] + lsum[rl6 + 5];
            float ss = lsq[rl6] + lsq[rl6 + 1] + lsq[rl6 + 2] + lsq[rl6 + 3] + lsq[rl6 + 4] + lsq[rl6 + 5];
            float m = s * (1.0f / 192.0f);
            mean[r] = m;
            rstd[r] = rsqrtf(ss * (1.0f / 192.0f) - m * m + 1e-5f);
        }
        #pragma unroll
        for (int j = 0; j < 2; ++j) {
            int h = nb + j * 16;
            float gg = ln1g[h], bb = ln1b[h];
            unsigned short* ap = (unsigned short*)Ap + (i * 6 + (h >> 5)) * 512
                               + ((h >> 3) & 3) * 128 + (h & 7) + q * 32;
            float v0 = (xres[i][j][0] - mean[0]) * rstd[0] * gg + bb;
            float v1 = (xres[i][j][1] - mean[1]) * rstd[1] * gg + bb;
            float v2 = (xres[i][j][2] - mean[2]) * rstd[2] * gg + bb;
            float v3 = (xres[i][j][3] - mean[3]) * rstd[3] * gg + bb;
            st2u(ap, ap + 8, v0, v1);
            st2u(ap + 16, ap + 24, v2, v3);
        }
    }
    __syncthreads();

    // FFN: hidden chunks of 192, hidden lives only in LDS (Lo)
    float4v acc2[4][2];
    #pragma unroll
    for (int i = 0; i < 4; ++i)
        #pragma unroll
        for (int j = 0; j < 2; ++j)
            acc2[i][j] = (float4v){0.f, 0.f, 0.f, 0.f};
    for (int hc = 0; hc < 4; ++hc) {
        float4v acc1[4][2];
        #pragma unroll
        for (int i = 0; i < 4; ++i)
            #pragma unroll
            for (int j = 0; j < 2; ++j)
                acc1[i][j] = (float4v){0.f, 0.f, 0.f, 0.f};
        #pragma unroll
        for (int kk = 0; kk < 6; ++kk) {
            short8 af[4], wf[2];
            #pragma unroll
            for (int j = 0; j < 2; ++j)
                wf[j] = *(const short8*)(W1s + (((size_t)(hc * 12 + w * 2 + j) * 6 + kk) << 9) + lane * 8);
            #pragma unroll
            for (int i = 0; i < 4; ++i)
                af[i] = *(const short8*)(Ap + ((i * 6 + kk) << 10) + lane * 16);
            #pragma unroll
            for (int i = 0; i < 4; ++i)
                #pragma unroll
                for (int j = 0; j < 2; ++j)
                    acc1[i][j] = __builtin_amdgcn_mfma_f32_16x16x32_bf16(af[i], wf[j], acc1[i][j], 0, 0, 0);
        }
        __syncthreads();
        #pragma unroll
        for (int i = 0; i < 4; ++i)
            #pragma unroll
            for (int j = 0; j < 2; ++j) {
                int h = nb + j * 16;
                float bv = B1[hc * 192 + h];
                unsigned short* lp = (unsigned short*)Lo + (i * 6 + (h >> 5)) * 512
                                   + ((h >> 3) & 3) * 128 + (h & 7) + q * 32;
                float v0 = gelu_f(acc1[i][j][0] + bv);
                float v1 = gelu_f(acc1[i][j][1] + bv);
                float v2 = gelu_f(acc1[i][j][2] + bv);
                float v3 = gelu_f(acc1[i][j][3] + bv);
                st2u(lp, lp + 8, v0, v1);
                st2u(lp + 16, lp + 24, v2, v3);
            }
        __syncthreads();
        #pragma unroll
        for (int kk = 0; kk < 6; ++kk) {
            short8 af[4], wf[2];
            #pragma unroll
            for (int j = 0; j < 2; ++j)
                wf[j] = *(const short8*)(W2s + (((size_t)(w * 2 + j) * 24 + hc * 6 + kk) << 9) + lane * 8);
            #pragma unroll
            for (int i = 0; i < 4; ++i)
                af[i] = *(const short8*)(Lo + ((i * 6 + kk) << 10) + lane * 16);
            #pragma unroll
            for (int i = 0; i < 4; ++i)
                #pragma unroll
                for (int j = 0; j < 2; ++j)
                    acc2[i][j] = __builtin_amdgcn_mfma_f32_16x16x32_bf16(af[i], wf[j], acc2[i][j], 0, 0, 0);
        }
    }

    // FFN residual; single vector X write (packed bf16)
    #pragma unroll
    for (int j = 0; j < 2; ++j) {
        int n = nb + j * 16;
        float bv = B2[n];
        #pragma unroll
        for (int i = 0; i < 4; ++i) {
            #pragma unroll
            for (int r = 0; r < 4; ++r)
                xres[i][j][r] += acc2[i][j][r] + bv;
            unsigned short* xp = Xres + XF(blockIdx.x * 4 + i, n) + q * 4;
            uintx2 o;
            o[0] = cvt_pk_bf16(xres[i][j][0], xres[i][j][1]);
            o[1] = cvt_pk_bf16(xres[i][j][2], xres[i][j][3]);
            *(uintx2*)xp = o;
        }
    }
    if (LASTB) return;

    // LN2 + next-block QKV
    #pragma unroll
    for (int i = 0; i < 4; ++i)
        #pragma unroll
        for (int r = 0; r < 4; ++r) {
            float s1 = xres[i][0][r] + xres[i][1][r];
            float s2 = xres[i][0][r] * xres[i][0][r] + xres[i][1][r] * xres[i][1][r];
            #pragma unroll
            for (int off = 1; off < 16; off <<= 1) {
                s1 += __shfl_xor(s1, off, 64);
                s2 += __shfl_xor(s2, off, 64);
            }
            if (r15 == 0) {
                int rl = i * 16 + q * 4 + r;
                lsum[rl * 6 + w] = s1;
                lsq[rl * 6 + w] = s2;
            }
        }
    __syncthreads();
    #pragma unroll
    for (int i = 0; i < 4; ++i) {
        float mean[4], rstd[4];
        #pragma unroll
        for (int r = 0; r < 4; ++r) {
            int rl6 = (i * 16 + q * 4 + r) * 6;
            float s  = lsum[rl6] + lsum[rl6 + 1] + lsum[rl6 + 2] + lsum[rl6 + 3] + lsum[rl6 + 4] + lsum[rl6 + 5];
            float ss = lsq[rl6] + lsq[rl6 + 1] + lsq[rl6 + 2] + lsq[rl6 + 3] + lsq[rl6 + 4] + lsq[rl6 + 5];
            float m = s * (1.0f / 192.0f);
            mean[r] = m;
            rstd[r] = rsqrtf(ss * (1.0f / 192.0f) - m * m + 1e-5f);
        }
        #pragma unroll
        for (int j = 0; j < 2; ++j) {
            int h = nb + j * 16;
            float gg = ln2g[h], bb = ln2b[h];
            unsigned short* ap = (unsigned short*)Ap + (i * 6 + (h >> 5)) * 512
                               + ((h >> 3) & 3) * 128 + (h & 7) + q * 32;
            float v0 = (xres[i][j][0] - mean[0]) * rstd[0] * gg + bb;
            float v1 = (xres[i][j][1] - mean[1]) * rstd[1] * gg + bb;
            float v2 = (xres[i][j][2] - mean[2]) * rstd[2] * gg + bb;
            float v3 = (xres[i][j][3] - mean[3]) * rstd[3] * gg + bb;
            st2u(ap, ap + 8, v0, v1);
            st2u(ap + 16, ap + 24, v2, v3);
        }
    }
    __syncthreads();

    // next-block QKV: direct global stores
    for (int seg = 0; seg < 3; ++seg) {
        float4v a2[4][2];
        #pragma unroll
        for (int i = 0; i < 4; ++i)
            #pragma unroll
            for (int j = 0; j < 2; ++j)
                a2[i][j] = (float4v){0.f, 0.f, 0.f, 0.f};
        #pragma unroll
        for (int kk = 0; kk < 6; ++kk) {
            short8 af[4], wf[2];
            #pragma unroll
            for (int j = 0; j < 2; ++j)
                wf[j] = *(const short8*)(QKVs + (((size_t)(seg * 12 + w * 2 + j) * 6 + kk) << 9) + lane * 8);
            #pragma unroll
            for (int i = 0; i < 4; ++i)
                af[i] = *(const short8*)(Ap + ((i * 6 + kk) << 10) + lane * 16);
            #pragma unroll
            for (int i = 0; i < 4; ++i)
                #pragma unroll
                for (int j = 0; j < 2; ++j)
                    a2[i][j] = __builtin_amdgcn_mfma_f32_16x16x32_bf16(af[i], wf[j], a2[i][j], 0, 0, 0);
        }
        unsigned short* dst = (seg == 0) ? Qb : (seg == 1) ? Kb : Vb;
        #pragma unroll
        for (int j = 0; j < 2; ++j) {
            int n = nb + j * 16;
            float bv = bqkv[seg * 192 + n];
            #pragma unroll
            for (int i = 0; i < 4; ++i) {
                int mrow = m0 + i * 16 + q * 4;
                #pragma unroll
                for (int r = 0; r < 4; ++r) {
                    float x = a2[i][j][r] + bv;
                    if (seg < 2) x = (x > 0.f) ? x + 1.f : __expf(x);
                    if (seg == 0) x *= 0.14433756729740643f;
                    dst[(size_t)(mrow + r) * 192 + n] = f2b(x);
                }
            }
        }
    }
}

// ---------------- ROW attention: one block per (row-group, head) ----------------
__global__ __launch_bounds__(256) void attn_rowh(const unsigned short* __restrict__ Qb,
                                                 const unsigned short* __restrict__ Kb,
                                                 const unsigned short* __restrict__ Vb,
                                                 unsigned short* __restrict__ O) {
    __shared__ __align__(16) unsigned char lds[58368];
    unsigned char* stg = lds;                              // [256 rows][208 B] K|V swizzled
    float* pub = (float*)lds;                              // [4][48][64] f32 (aliases stg)
    unsigned short* kvs = (unsigned short*)(lds + 49152);  // [64][72] shorts
    const int tid = threadIdx.x;
    const int lane = tid & 63;
    const int wq = tid >> 6;                 // ks quarter 0..3
    const int h = blockIdx.x & 3;
    const size_t base = (size_t)(blockIdx.x >> 2) * 256;
    const int q = lane >> 4, r15 = lane & 15, q8 = q * 8;

    // stage: 256 rows x (48K + 48V) shorts, row stride 208B, XOR ((row>>3)&3)<<5
    short8 rg[12];
    #pragma unroll
    for (int it = 0; it < 12; ++it) {
        int u = it * 256 + tid;
        int row = u / 12, c8 = u - (u / 12) * 12;
        const unsigned short* gp = (c8 < 6)
            ? (Kb + (base + row) * 192 + h * 48 + c8 * 8)
            : (Vb + (base + row) * 192 + h * 48 + (c8 - 6) * 8);
        rg[it] = *(const short8*)gp;
    }
    #pragma unroll
    for (int it = 0; it < 12; ++it) {
        int u = it * 256 + tid;
        int row = u / 12, c8 = u - (u / 12) * 12;
        int ba = (row * 208 + c8 * 16) ^ (((row >> 3) & 3) << 5);
        *(short8*)(stg + ba) = rg[it];
    }
    __syncthreads();

    short8 onesf;
    #pragma unroll
    for (int e = 0; e < 8; ++e) onesf[e] = (short)0x3F80;

    float4v kv[3][4];
    #pragma unroll
    for (int i = 0; i < 3; ++i)
        #pragma unroll
        for (int j = 0; j < 4; ++j)
            kv[i][j] = (float4v){0.f, 0.f, 0.f, 0.f};

    #pragma unroll
    for (int sc = 0; sc < 2; ++sc) {
        int ks0 = wq * 64 + sc * 32;
        short8 af[3], bf[3];
        #pragma unroll
        for (int t = 0; t < 3; ++t) {
            #pragma unroll
            for (int j = 0; j < 8; ++j) {
                int row = ks0 + q8 + j;
                int sw = ((row >> 3) & 3) << 5;
                af[t][j] = *(const short*)(stg + ((row * 208 + (t * 16 + r15) * 2) ^ sw));
                bf[t][j] = *(const short*)(stg + ((row * 208 + 96 + (t * 16 + r15) * 2) ^ sw));
            }
        }
        #pragma unroll
        for (int i = 0; i < 3; ++i) {
            #pragma unroll
            for (int j = 0; j < 3; ++j)
                kv[i][j] = __builtin_amdgcn_mfma_f32_16x16x32_bf16(af[i], bf[j], kv[i][j], 0, 0, 0);
            kv[i][3] = __builtin_amdgcn_mfma_f32_16x16x32_bf16(af[i], onesf, kv[i][3], 0, 0, 0);
        }
    }
    __syncthreads();                         // staging reads done; pub/kvs may reuse space

    // publish partial KV states (f32)
    {
        float* kp = pub + wq * 3072;
        #pragma unroll
        for (int i = 0; i < 3; ++i)
            #pragma unroll
            for (int j = 0; j < 4; ++j)
                #pragma unroll
                for (int r = 0; r < 4; ++r)
                    kp[((i * 4 + j) * 4 + r) * 64 + lane] = kv[i][j][r];
    }
    __syncthreads();

    // zero kvs cols 48..63 (k_ch beyond 47 must be 0 for kk=1 fragments)
    {
        unsigned int* kz = (unsigned int*)kvs;
        #pragma unroll
        for (int z = 0; z < 2; ++z) {
            int zz = z * 256 + tid;
            int zr = zz >> 3, zc = zz & 7;
            kz[zr * 36 + 24 + zc] = 0;
        }
    }
    // combine: wave wq sums V-block j==wq across 4 partials, emits kvs rows
    #pragma unroll
    for (int i = 0; i < 3; ++i)
        #pragma unroll
        for (int r = 0; r < 4; ++r) {
            int idx = ((i * 4 + wq) * 4 + r) * 64 + lane;
            float s = pub[idx] + pub[3072 + idx] + pub[6144 + idx] + pub[9216 + idx];
            int kc = i * 16 + q * 4 + r;
            if (wq < 3)
                kvs[(wq * 16 + r15) * 72 + kc] = f2b(s);
            else
                kvs[(48 + r15) * 72 + kc] = (r15 == 0) ? f2b(s) : (unsigned short)0;
        }
    __syncthreads();

    short8 bkv[2][4];
    #pragma unroll
    for (int kk = 0; kk < 2; ++kk)
        #pragma unroll
        for (int t = 0; t < 4; ++t)
            bkv[kk][t] = *(const short8*)&kvs[(t * 16 + r15) * 72 + kk * 32 + q8];

    #pragma unroll
    for (int m = 0; m < 4; ++m) {
        int mt = wq * 4 + m;
        float4v o[4];
        #pragma unroll
        for (int t = 0; t < 4; ++t) o[t] = (float4v){0.f, 0.f, 0.f, 0.f};
        #pragma unroll
        for (int kk = 0; kk < 2; ++kk) {
            const unsigned short* qp = Qb + (base + (size_t)(mt * 16 + r15)) * 192
                                       + h * 48 + kk * 32 + q8;
            short8 aq = *(const short8*)qp;
            #pragma unroll
            for (int t = 0; t < 4; ++t)
                o[t] = __builtin_amdgcn_mfma_f32_16x16x32_bf16(aq, bkv[kk][t], o[t], 0, 0, 0);
        }
        #pragma unroll
        for (int r = 0; r < 4; ++r) {
            float den = __shfl(o[3][r], q << 4);
            float z = 1.0f / (den + 1e-6f);
            int n = mt * 16 + q * 4 + r;
            unsigned short* op = O + (base + (size_t)n) * 192 + h * 48;
            #pragma unroll
            for (int t = 0; t < 3; ++t)
                op[t * 16 + r15] = f2b(o[t][r] * z);
        }
    }
}

// ---------------- COL attention (pixel-major K/V, swizzled LDS gather) ----------------
template<int N, int MSTR>
__global__ __launch_bounds__(256) void attn_axial(const unsigned short* __restrict__ Qb,
                                                  const unsigned short* __restrict__ Kb,
                                                  const unsigned short* __restrict__ Vb,
                                                  unsigned short* __restrict__ O) {
    __shared__ unsigned short KV[32][400];
    __shared__ unsigned short kvs[4][64][72];
    unsigned char* kvb = (unsigned char*)KV;
    const int tid = threadIdx.x;
    const int lane = tid & 63;
    const int w = tid >> 6;
    const int q = lane >> 4, r15 = lane & 15, q8 = q * 8;
    size_t base;
    if (MSTR == 1) base = (size_t)blockIdx.x * N;
    else           base = (size_t)(blockIdx.x >> 8) * 16384 + (blockIdx.x & 255);

    unsigned int* kz = (unsigned int*)&kvs[w][0][0];
    #pragma unroll
    for (int ii = 0; ii < 36; ++ii) kz[lane + ii * 64] = 0;

    short8 onesf;
    #pragma unroll
    for (int e = 0; e < 8; ++e) onesf[e] = (short)0x3F80;

    float4v kv[3][4];
    #pragma unroll
    for (int i = 0; i < 3; ++i)
        #pragma unroll
        for (int j = 0; j < 4; ++j)
            kv[i][j] = (float4v){0.f, 0.f, 0.f, 0.f};

    for (int ks = 0; ks < N; ks += 32) {
        #pragma unroll
        for (int it = 0; it < 6; ++it) {
            int cc = tid + it * 256;
            int row = cc / 48, c8 = cc - (cc / 48) * 48;
            size_t poff = (base + (size_t)(ks + row) * MSTR) * 192;
            const unsigned short* gp = (c8 < 24) ? (Kb + poff + c8 * 8) : (Vb + poff + (c8 - 24) * 8);
            int ba = (row * 800 + c8 * 16) ^ (((row >> 3) & 3) << 5);
            *(short8*)(kvb + ba) = *(const short8*)gp;
        }
        __syncthreads();
        short8 af[3], bf[3];
        #pragma unroll
        for (int t = 0; t < 3; ++t) {
            #pragma unroll
            for (int j = 0; j < 8; ++j) {
                int row = q8 + j;
                int sw = ((row >> 3) & 3) << 5;
                af[t][j] = *(short*)(kvb + ((row * 800 + (w * 48 + t * 16 + r15) * 2) ^ sw));
                bf[t][j] = *(short*)(kvb + ((row * 800 + 384 + (w * 48 + t * 16 + r15) * 2) ^ sw));
            }
        }
        #pragma unroll
        for (int i = 0; i < 3; ++i) {
            #pragma unroll
            for (int j = 0; j < 3; ++j)
                kv[i][j] = __builtin_amdgcn_mfma_f32_16x16x32_bf16(af[i], bf[j], kv[i][j], 0, 0, 0);
            kv[i][3] = __builtin_amdgcn_mfma_f32_16x16x32_bf16(af[i], onesf, kv[i][3], 0, 0, 0);
        }
        __syncthreads();
    }

    #pragma unroll
    for (int i = 0; i < 3; ++i) {
        #pragma unroll
        for (int j = 0; j < 3; ++j)
            #pragma unroll
            for (int r = 0; r < 4; ++r)
                kvs[w][j * 16 + r15][i * 16 + q * 4 + r] = f2b(kv[i][j][r]);
        if (r15 == 0)
            #pragma unroll
            for (int r = 0; r < 4; ++r)
                kvs[w][48][i * 16 + q * 4 + r] = f2b(kv[i][3][r]);
    }

    short8 bkv[2][4];
    #pragma unroll
    for (int kk = 0; kk < 2; ++kk)
        #pragma unroll
        for (int t = 0; t < 4; ++t)
            bkv[kk][t] = *(const short8*)&kvs[w][t * 16 + r15][kk * 32 + q8];

    for (int mt = 0; mt < N / 16; ++mt) {
        float4v o[4];
        #pragma unroll
        for (int t = 0; t < 4; ++t) o[t] = (float4v){0.f, 0.f, 0.f, 0.f};
        #pragma unroll
        for (int kk = 0; kk < 2; ++kk) {
            const unsigned short* qp = Qb + (base + (size_t)(mt * 16 + r15) * MSTR) * 192
                                       + w * 48 + kk * 32 + q8;
            short8 aq = *(const short8*)qp;
            #pragma unroll
            for (int t = 0; t < 4; ++t)
                o[t] = __builtin_amdgcn_mfma_f32_16x16x32_bf16(aq, bkv[kk][t], o[t], 0, 0, 0);
        }
        #pragma unroll
        for (int r = 0; r < 4; ++r) {
            float den = __shfl(o[3][r], q << 4);
            float z = 1.0f / (den + 1e-6f);
            int n = mt * 16 + q * 4 + r;
            unsigned short* op = O + (base + (size_t)n * MSTR) * 192 + w * 48;
            #pragma unroll
            for (int t = 0; t < 3; ++t)
                op[t * 16 + r15] = f2b(o[t][r] * z);
        }
    }
}

__global__ __launch_bounds__(256) void final_kernel(const unsigned short* __restrict__ X,
                                                    const float* __restrict__ pw_w,
                                                    const float* __restrict__ pw_b, float* __restrict__ out) {
    int wave = threadIdx.x >> 6;
    int lane = threadIdx.x & 63;
    int p = blockIdx.x * 4 + wave;
    const unsigned short* xp = X + XF(p >> 4, 0) + (p & 15);
    float s = b2f(xp[(size_t)lane << 4]) * pw_w[lane]
            + b2f(xp[(size_t)(lane + 64) << 4]) * pw_w[lane + 64]
            + b2f(xp[(size_t)(lane + 128) << 4]) * pw_w[lane + 128];
    #pragma unroll
    for (int off = 32; off; off >>= 1) s += __shfl_xor(s, off, 64);
    if (lane == 0) {
        float o = s + pw_b[0];
        float e = expf(o);
        out[p] = 1.0f - 1.0f / (2.0f + e);
    }
}

extern "C" void kernel_launch(void* const* d_in, const int* in_sizes, int n_in,
                              void* d_out, int out_size, void* d_ws, size_t ws_size,
                              hipStream_t stream) {
    const int*   tokens = (const int*)  d_in[0];
    const float* emb    = (const float*)d_in[1];
    const float* proj_w = (const float*)d_in[2];
    const float* proj_b = (const float*)d_in[3];
    const float* ln_g   = (const float*)d_in[4];
    const float* ln_b   = (const float*)d_in[5];
    const float* wq     = (const float*)d_in[6];
    const float* wk     = (const float*)d_in[7];
    const float* wv     = (const float*)d_in[8];
    const float* wo     = (const float*)d_in[9];
    const float* bq     = (const float*)d_in[10];
    const float* bk     = (const float*)d_in[11];
    const float* bv     = (const float*)d_in[12];
    const float* bo     = (const float*)d_in[13];
    const float* ffn_w1 = (const float*)d_in[14];
    const float* ffn_b1 = (const float*)d_in[15];
    const float* ffn_w2 = (const float*)d_in[16];
    const float* ffn_b2 = (const float*)d_in[17];
    const float* pw_w   = (const float*)d_in[18];
    const float* pw_b   = (const float*)d_in[19];

    unsigned short* X    = (unsigned short*)d_ws;        // bf16 residual stream (fragment-major)
    unsigned short* Ho   = X + BUF;
    unsigned short* Qb   = Ho + BUF;
    unsigned short* Kb   = Qb + BUF;
    unsigned short* Vb   = Kb + BUF;
    unsigned short* Eg   = Vb + BUF;                     // NP*64
    unsigned short* wqkvb = Eg + (size_t)NP * 64;
    const int QKVSZ = NBLK * 2 * 576 * CCH;
    const int WSZ   = NBLK * 2 * CCH * CCH;
    const int FSZ   = NBLK * 768 * CCH;
    unsigned short* wob = wqkvb + QKVSZ;
    unsigned short* w1b = wob + WSZ;
    unsigned short* w2b = w1b + FSZ;
    unsigned short* pjb = w2b + FSZ;                     // 12288
    float* bqkvb = (float*)(pjb + 12288 + 32);
    float* Xt = (float*)Qb;                              // proj tmp fp32 (spans Qb+Kb, free pre-loop)

    wqkv_swz<<<QKVSZ / 256, 256, 0, stream>>>(wq, wk, wv, wqkvb);
    bqkv_concat<<<27, 256, 0, stream>>>(bq, bk, bv, bqkvb);
    swz_conv<192, 192><<<(WSZ + 255) / 256, 256, 0, stream>>>(wo, wob, NBLK * 2);
    swz_conv<768, 192><<<(FSZ + 255) / 256, 256, 0, stream>>>(ffn_w1, w1b, NBLK);
    swz_conv<192, 768><<<(FSZ + 255) / 256, 256, 0, stream>>>(ffn_w2, w2b, NBLK);
    swz_conv<192, 64><<<48, 256, 0, stream>>>(proj_w, pjb, 1);

    gather_kernel<<<NP * 64 / 256, 256, 0, stream>>>(tokens, emb, Eg);
    mm192<64, 1><<<dim3(1, NP / 64), 256, 0, stream>>>(Eg, pjb, proj_b,
                                                       nullptr, nullptr, nullptr, Xt, NP, CCH, 64);
    rotary_ln_kernel<<<NP / 4, 256, 0, stream>>>(Xt, X, Ho, ln_g, ln_b);
    mm192<128, 0><<<dim3(3, NP / 128), 256, 0, stream>>>(Ho, wqkvb, bqkvb,
                                                         Qb, Kb, Vb, nullptr, NP, 576, CCH);

    for (int i = 0; i < NBLK; ++i) {
        size_t wi0 = (size_t)(i * 2), wi1 = wi0 + 1;
        attn_rowh<<<BB * SS * 4, 256, 0, stream>>>(Qb, Kb, Vb, Ho);
        wo_qkv<<<NP / 32, 256, 0, stream>>>(Ho, wob + wi0 * CCH * CCH, bo + wi0 * CCH, X,
                                            ln_g + (size_t)(i * 3 + 1) * CCH, ln_b + (size_t)(i * 3 + 1) * CCH,
                                            wqkvb + wi1 * 576 * CCH, bqkvb + wi1 * 576, Qb, Kb, Vb);
        attn_axial<SS, LL><<<BB * LL, 256, 0, stream>>>(Qb, Kb, Vb, Ho);
        if (i < NBLK - 1) {
            size_t wn0 = (size_t)((i + 1) * 2);
            wo_ffn_qkv<false><<<NP / 64, 384, 0, stream>>>(
                Ho, wob + wi1 * CCH * CCH, bo + wi1 * CCH, X,
                ln_g + (size_t)(i * 3 + 2) * CCH, ln_b + (size_t)(i * 3 + 2) * CCH,
                w1b + (size_t)i * 768 * CCH, ffn_b1 + (size_t)i * 768,
                w2b + (size_t)i * CCH * 768, ffn_b2 + (size_t)i * CCH,
                ln_g + (size_t)((i + 1) * 3) * CCH, ln_b + (size_t)((i + 1) * 3) * CCH,
                wqkvb + wn0 * 576 * CCH, bqkvb + wn0 * 576, Qb, Kb, Vb);
        } else {
            wo_ffn_qkv<true><<<NP / 64, 384, 0, stream>>>(
                Ho, wob + wi1 * CCH * CCH, bo + wi1 * CCH, X,
                ln_g + (size_t)(i * 3 + 2) * CCH, ln_b + (size_t)(i * 3 + 2) * CCH,
                w1b + (size_t)i * 768 * CCH, ffn_b1 + (size_t)i * 768,
                w2b + (size_t)i * CCH * 768, ffn_b2 + (size_t)i * CCH,
                nullptr, nullptr, nullptr, nullptr, nullptr, nullptr, nullptr);
        }
    }
    final_kernel<<<NP / 4, 256, 0, stream>>>(X, pw_w, pw_b, (float*)d_out);
}

// Round 13
// 854.153 us; speedup vs baseline: 1.3651x; 1.3651x over previous
//
#include <hip/hip_runtime.h>
#include <hip/hip_bf16.h>
#include <math.h>

#define NBLK 6
#define NH 4
#define CCH 192
#define BB 2
#define SS 64
#define LL 256
#define DH 48
#define NP (BB*SS*LL)            // 32768 pixels
#define BUF ((size_t)NP*CCH)

typedef __attribute__((ext_vector_type(8))) short short8;
typedef __attribute__((ext_vector_type(4))) float float4v;
typedef __attribute__((ext_vector_type(2))) unsigned int uintx2;

__device__ __forceinline__ unsigned short f2b(float f) {
    union { float f; unsigned int u; } v; v.f = f;
    unsigned int r = v.u + 0x7FFF + ((v.u >> 16) & 1);
    return (unsigned short)(r >> 16);
}
__device__ __forceinline__ float b2f(unsigned short u) {
    union { unsigned int u; float f; } v; v.u = ((unsigned int)u) << 16;
    return v.f;
}
// packed f32x2 -> bf16x2 (RNE)
__device__ __forceinline__ unsigned int cvt_pk_bf16(float lo, float hi) {
    unsigned int r;
    asm("v_cvt_pk_bf16_f32 %0, %1, %2" : "=v"(r) : "v"(lo), "v"(hi));
    return r;
}
__device__ __forceinline__ void st2u(unsigned short* p0, unsigned short* p1, float a, float b) {
    unsigned int u = cvt_pk_bf16(a, b);
    *p0 = (unsigned short)u;
    *p1 = (unsigned short)(u >> 16);
}
__device__ __forceinline__ void xf_unpack(uintx2 u, float* f) {
    union { unsigned int x; float ff; } t;
    t.x = u[0] << 16;          f[0] = t.ff;
    t.x = u[0] & 0xffff0000u;  f[1] = t.ff;
    t.x = u[1] << 16;          f[2] = t.ff;
    t.x = u[1] & 0xffff0000u;  f[3] = t.ff;
}
// exact-GELU via branch-free A&S 7.1.26 erf (|err| <= 1.5e-7)
__device__ __forceinline__ float gelu_f(float v) {
    float z = v * 0.7071067811865475f;
    float a = fabsf(z);
    float t = __builtin_amdgcn_rcpf(fmaf(0.3275911f, a, 1.0f));
    float p = fmaf(t, 1.061405429f, -1.453152027f);
    p = fmaf(t, p, 1.421413741f);
    p = fmaf(t, p, -0.284496736f);
    p = fmaf(t, p, 0.254829592f);
    p *= t;
    float e = __expf(-a * a);
    float er = fmaf(-p, e, 1.0f);
    er = __builtin_copysignf(er, z);
    return 0.5f * v * (1.0f + er);
}
__device__ __forceinline__ void async_lds16(const void* g, void* l) {
    __builtin_amdgcn_global_load_lds(
        (const __attribute__((address_space(1))) unsigned int*)g,
        (__attribute__((address_space(3))) unsigned int*)l, 16, 0, 0);
}

// fragment-major residual layout: element (p,c) lives at ((p>>4)*192 + c)*16 + (p&15)
#define XF(p16, c) (((size_t)(p16) * 192 + (c)) << 4)

// ---------- weight prep: fragment-major swizzle ----------
template<int N, int K>
__global__ void swz_conv(const float* __restrict__ src, unsigned short* __restrict__ dst, int layers) {
    int s = blockIdx.x * 256 + threadIdx.x;
    if (s >= layers * N * K) return;
    int li = s / (N * K);
    int t = s - li * (N * K);
    constexpr int KC = K / 32;
    int chunk = t >> 9, c = t & 511;
    int g = chunk / KC, sk = chunk - g * KC;
    int lane = c >> 3, ko = c & 7;
    int n = g * 16 + (lane & 15), k = sk * 32 + (lane >> 4) * 8 + ko;
    dst[s] = f2b(src[(size_t)li * N * K + (size_t)n * K + k]);
}
__global__ void wqkv_swz(const float* __restrict__ wq, const float* __restrict__ wk,
                         const float* __restrict__ wv, unsigned short* __restrict__ d) {
    int s = blockIdx.x * 256 + threadIdx.x;          // 12*576*192
    int wi = s / (576 * 192);
    int t = s - wi * 576 * 192;
    int chunk = t >> 9, c = t & 511;
    int g = chunk / 6, sk = chunk - g * 6;
    int lane = c >> 3, ko = c & 7;
    int n = g * 16 + (lane & 15), k = sk * 32 + (lane >> 4) * 8 + ko;
    int sg = n / 192, row = n - sg * 192;
    const float* src = (sg == 0) ? wq : (sg == 1) ? wk : wv;
    d[s] = f2b(src[(size_t)wi * 192 * 192 + (size_t)row * 192 + k]);
}
__global__ void bqkv_concat(const float* __restrict__ bq, const float* __restrict__ bk,
                            const float* __restrict__ bv, float* __restrict__ d) {
    int idx = blockIdx.x * 256 + threadIdx.x;        // 12*576
    if (idx >= NBLK * 2 * 576) return;
    int wi = idx / 576, n = idx - (idx / 576) * 576;
    int sg = n / 192, row = n - sg * 192;
    const float* src = (sg == 0) ? bq : (sg == 1) ? bk : bv;
    d[idx] = src[wi * CCH + row];
}

__global__ void gather_kernel(const int* __restrict__ tokens, const float* __restrict__ emb,
                              unsigned short* __restrict__ Eg) {
    int idx = blockIdx.x * 256 + threadIdx.x;   // NP*64
    int p = idx >> 6, c = idx & 63;
    Eg[idx] = f2b(emb[tokens[p] * 64 + c]);
}

// rotary + first LayerNorm fused; X stored bf16 fragment-major (storage only — math fp32)
__global__ __launch_bounds__(256) void rotary_ln_kernel(const float* __restrict__ Xt,
                                                        unsigned short* __restrict__ X,
                                                        unsigned short* __restrict__ Hn,
                                                        const float* __restrict__ g, const float* __restrict__ b) {
    int wave = threadIdx.x >> 6;
    int lane = threadIdx.x & 63;
    int p = blockIdx.x * 4 + wave;
    int l = p & (LL - 1);
    const float* xp = Xt + (size_t)p * CCH;
    float v[3];
    #pragma unroll
    for (int i = 0; i < 3; ++i) {
        int c = lane + i * 64;
        int j = c % 96;
        float inv = expf((float)(2 * j) * (-9.210340371976184f / 192.0f));
        float ang = (float)l * inv;
        float part = (c < 96) ? -xp[c + 96] : xp[c - 96];
        v[i] = xp[c] * cosf(ang) + part * sinf(ang);
    }
    float s = v[0] + v[1] + v[2];
    float qq = v[0] * v[0] + v[1] * v[1] + v[2] * v[2];
    #pragma unroll
    for (int off = 32; off; off >>= 1) {
        s += __shfl_xor(s, off, 64);
        qq += __shfl_xor(qq, off, 64);
    }
    float mean = s * (1.0f / 192.0f);
    float var = qq * (1.0f / 192.0f) - mean * mean;
    float r = rsqrtf(var + 1e-5f);
    unsigned short* hp = Hn + (size_t)p * CCH;
    const int p16 = p >> 4, pr = p & 15;
    #pragma unroll
    for (int i = 0; i < 3; ++i) {
        int c = lane + i * 64;
        X[XF(p16, c) + pr] = f2b(v[i]);
        hp[c] = f2b((v[i] - mean) * r * g[c] + b[c]);
    }
}

// ---------------- bf16 MFMA GEMM (pre-loop only: proj, block-0 QKV) ----------------
template<int MT, int EPI>
__global__ __launch_bounds__(256, (MT == 128) ? 3 : 4)
void mm192(const unsigned short* __restrict__ A, const unsigned short* __restrict__ Wsw,
           const float* __restrict__ bias,
           unsigned short* __restrict__ O0, unsigned short* __restrict__ O1,
           unsigned short* __restrict__ O2,
           float* __restrict__ Of,
           int M, int N, int K) {
    constexpr int NI = MT / 32;
    __shared__ __align__(16) unsigned char lds[(MT == 128) ? 51200 : 28672];
    const int tid = threadIdx.x;
    const int lane = tid & 63;
    const int w = tid >> 6;
    const int wm = w >> 1, wn = w & 1;
    const int m0 = blockIdx.y * MT;
    const int g0 = blockIdx.x * 12;
    const int q = lane >> 4;
    const int q8 = q << 3;
    const int r15 = lane & 15;
    const int KC = K >> 5;

    for (int c = w; c < (MT / 16) * KC; c += 4) {
        int g = c / KC, sk = c - g * KC;
        async_lds16(A + (size_t)(m0 + g * 16 + r15) * K + sk * 32 + q8, lds + c * 1024);
    }

    float4v acc[NI][6];
    #pragma unroll
    for (int i = 0; i < NI; ++i)
        #pragma unroll
        for (int j = 0; j < 6; ++j)
            acc[i][j] = (float4v){0.f, 0.f, 0.f, 0.f};

    __syncthreads();

    for (int sk = 0; sk < KC; ++sk) {
        short8 af[NI], wf[6];
        #pragma unroll
        for (int j = 0; j < 6; ++j)
            wf[j] = *(const short8*)(Wsw + (((size_t)(g0 + wn * 6 + j) * KC + sk) << 9) + lane * 8);
        #pragma unroll
        for (int i = 0; i < NI; ++i)
            af[i] = *(const short8*)(lds + (((wm * NI + i) * KC + sk) << 10) + lane * 16);
        #pragma unroll
        for (int i = 0; i < NI; ++i)
            #pragma unroll
            for (int j = 0; j < 6; ++j)
                acc[i][j] = __builtin_amdgcn_mfma_f32_16x16x32_bf16(af[i], wf[j], acc[i][j], 0, 0, 0);
    }

    const int nb = blockIdx.x * 192 + wn * 96 + r15;
    const int mb = m0 + wm * (MT / 2) + q * 4;

    if (EPI == 0) {
        const int bx = blockIdx.x;
        unsigned short* dst = (bx == 0) ? O0 : (bx == 1) ? O1 : O2;
        #pragma unroll
        for (int j = 0; j < 6; ++j) {
            int n = nb + j * 16;                      // global 576-wide col (bias)
            int col = wn * 96 + j * 16 + r15;         // local 192-wide col (store)
            float bv = bias[n];
            #pragma unroll
            for (int i = 0; i < NI; ++i) {
                int mrow = wm * (MT / 2) + i * 16 + q * 4;
                #pragma unroll
                for (int r = 0; r < 4; ++r) {
                    float v = acc[i][j][r] + bv;
                    if (bx < 2) v = (v > 0.f) ? v + 1.f : __expf(v);
                    if (bx == 0) v *= 0.14433756729740643f;
                    dst[(size_t)(m0 + mrow + r) * 192 + col] = f2b(v);
                }
            }
        }
    } else {
        #pragma unroll
        for (int j = 0; j < 6; ++j) {
            int n = nb + j * 16;
            float bv = bias[n];
            #pragma unroll
            for (int i = 0; i < NI; ++i) {
                int mrow = mb + i * 16;
                #pragma unroll
                for (int r = 0; r < 4; ++r)
                    Of[(size_t)(mrow + r) * N + n] = acc[i][j][r] + bv;
            }
        }
    }
}

// ======== fused per-pixel GEMM chains ========

// ---- WO + residual + LN + QKV (32 rows/block, 256 threads — R3 config, best measured) ----
// LDS (25600 B): Lo [0,12288) staging | stats [12288,13312) | Ap [13312,25600)
__global__ __launch_bounds__(256, 4)
void wo_qkv(const unsigned short* __restrict__ Ho,
            const unsigned short* __restrict__ WOs, const float* __restrict__ BO,
            unsigned short* __restrict__ Xres,
            const float* __restrict__ lng, const float* __restrict__ lnb,
            const unsigned short* __restrict__ QKVs, const float* __restrict__ bqkv,
            unsigned short* __restrict__ Qb, unsigned short* __restrict__ Kb,
            unsigned short* __restrict__ Vb) {
    __shared__ __align__(16) unsigned char lds[25600];
    unsigned char* Lo = lds;
    float* lsum = (float*)(lds + 12288);     // [32][4]
    float* lsq  = lsum + 128;
    unsigned char* Ap = lds + 13312;
    const int tid = threadIdx.x;
    const int lane = tid & 63;
    const int w = tid >> 6;                  // 0..3
    const int m0 = blockIdx.x * 32;
    const int q = lane >> 4, q8 = q << 3, r15 = lane & 15;
    const int nb = w * 48 + r15;

    #pragma unroll
    for (int it = 0; it < 3; ++it) {
        int c = it * 4 + w;                  // 0..11
        int g = c / 6, sk = c - g * 6;
        async_lds16(Ho + (size_t)(m0 + g * 16 + r15) * 192 + sk * 32 + q8, Lo + c * 1024);
    }
    __syncthreads();

    float4v acc[2][3];
    #pragma unroll
    for (int i = 0; i < 2; ++i)
        #pragma unroll
        for (int j = 0; j < 3; ++j)
            acc[i][j] = (float4v){0.f, 0.f, 0.f, 0.f};
    #pragma unroll
    for (int kk = 0; kk < 6; ++kk) {
        short8 af[2], wf[3];
        #pragma unroll
        for (int j = 0; j < 3; ++j)
            wf[j] = *(const short8*)(WOs + (((size_t)(w * 3 + j) * 6 + kk) << 9) + lane * 8);
        #pragma unroll
        for (int i = 0; i < 2; ++i)
            af[i] = *(const short8*)(Lo + ((i * 6 + kk) << 10) + lane * 16);
        #pragma unroll
        for (int i = 0; i < 2; ++i)
            #pragma unroll
            for (int j = 0; j < 3; ++j)
                acc[i][j] = __builtin_amdgcn_mfma_f32_16x16x32_bf16(af[i], wf[j], acc[i][j], 0, 0, 0);
    }

    // residual (vector 8B read-modify-write, fragment-major X), LN stats
    #pragma unroll
    for (int j = 0; j < 3; ++j) {
        int n = nb + j * 16;
        float bv = BO[n];
        #pragma unroll
        for (int i = 0; i < 2; ++i) {
            unsigned short* xp = Xres + XF(blockIdx.x * 2 + i, n) + q * 4;
            uintx2 u = *(const uintx2*)xp;
            float f[4]; xf_unpack(u, f);
            #pragma unroll
            for (int r = 0; r < 4; ++r) acc[i][j][r] += bv + f[r];
            uintx2 o;
            o[0] = cvt_pk_bf16(acc[i][j][0], acc[i][j][1]);
            o[1] = cvt_pk_bf16(acc[i][j][2], acc[i][j][3]);
            *(uintx2*)xp = o;
        }
    }
    #pragma unroll
    for (int i = 0; i < 2; ++i)
        #pragma unroll
        for (int r = 0; r < 4; ++r) {
            float s1 = acc[i][0][r] + acc[i][1][r] + acc[i][2][r];
            float s2 = acc[i][0][r] * acc[i][0][r] + acc[i][1][r] * acc[i][1][r] + acc[i][2][r] * acc[i][2][r];
            #pragma unroll
            for (int off = 1; off < 16; off <<= 1) {
                s1 += __shfl_xor(s1, off, 64);
                s2 += __shfl_xor(s2, off, 64);
            }
            if (r15 == 0) {
                int rl = i * 16 + q * 4 + r;
                lsum[rl * 4 + w] = s1;
                lsq[rl * 4 + w] = s2;
            }
        }
    __syncthreads();
    #pragma unroll
    for (int i = 0; i < 2; ++i) {
        float mean[4], rstd[4];
        #pragma unroll
        for (int r = 0; r < 4; ++r) {
            int rl4 = (i * 16 + q * 4 + r) * 4;
            float s  = lsum[rl4] + lsum[rl4 + 1] + lsum[rl4 + 2] + lsum[rl4 + 3];
            float ss = lsq[rl4] + lsq[rl4 + 1] + lsq[rl4 + 2] + lsq[rl4 + 3];
            float m = s * (1.0f / 192.0f);
            mean[r] = m;
            rstd[r] = rsqrtf(ss * (1.0f / 192.0f) - m * m + 1e-5f);
        }
        #pragma unroll
        for (int j = 0; j < 3; ++j) {
            int h = nb + j * 16;
            float gg = lng[h], bb = lnb[h];
            unsigned short* ap = (unsigned short*)Ap + (i * 6 + (h >> 5)) * 512
                               + ((h >> 3) & 3) * 128 + (h & 7) + q * 32;
            float v0 = (acc[i][j][0] - mean[0]) * rstd[0] * gg + bb;
            float v1 = (acc[i][j][1] - mean[1]) * rstd[1] * gg + bb;
            float v2 = (acc[i][j][2] - mean[2]) * rstd[2] * gg + bb;
            float v3 = (acc[i][j][3] - mean[3]) * rstd[3] * gg + bb;
            st2u(ap, ap + 8, v0, v1);
            st2u(ap + 16, ap + 24, v2, v3);
        }
    }
    __syncthreads();

    // QKV: 3 segments, direct global stores
    for (int seg = 0; seg < 3; ++seg) {
        float4v a2[2][3];
        #pragma unroll
        for (int i = 0; i < 2; ++i)
            #pragma unroll
            for (int j = 0; j < 3; ++j)
                a2[i][j] = (float4v){0.f, 0.f, 0.f, 0.f};
        #pragma unroll
        for (int kk = 0; kk < 6; ++kk) {
            short8 af[2], wf[3];
            #pragma unroll
            for (int j = 0; j < 3; ++j)
                wf[j] = *(const short8*)(QKVs + (((size_t)(seg * 12 + w * 3 + j) * 6 + kk) << 9) + lane * 8);
            #pragma unroll
            for (int i = 0; i < 2; ++i)
                af[i] = *(const short8*)(Ap + ((i * 6 + kk) << 10) + lane * 16);
            #pragma unroll
            for (int i = 0; i < 2; ++i)
                #pragma unroll
                for (int j = 0; j < 3; ++j)
                    a2[i][j] = __builtin_amdgcn_mfma_f32_16x16x32_bf16(af[i], wf[j], a2[i][j], 0, 0, 0);
        }
        unsigned short* dst = (seg == 0) ? Qb : (seg == 1) ? Kb : Vb;
        #pragma unroll
        for (int j = 0; j < 3; ++j) {
            int n = nb + j * 16;
            float bv = bqkv[seg * 192 + n];
            #pragma unroll
            for (int i = 0; i < 2; ++i) {
                int mrow = m0 + i * 16 + q * 4;
                #pragma unroll
                for (int r = 0; r < 4; ++r) {
                    float x = a2[i][j][r] + bv;
                    if (seg < 2) x = (x > 0.f) ? x + 1.f : __expf(x);
                    if (seg == 0) x *= 0.14433756729740643f;
                    dst[(size_t)(mrow + r) * 192 + n] = f2b(x);
                }
            }
        }
    }
}

// ---- WO + residual(reg) + LN + FFN + residual + LN + next-QKV (64 rows/block) ----
// 64 rows/wave halves L2 weight traffic (measured R6: FETCH 24.2->16.3 MB).
// LDS (51200 B): Lo [0,24576) staging/hidden | stats [24576,26624) | Ap [26624,51200)
template<bool LASTB>
__global__ __launch_bounds__(256, 2)
void wo_ffn_qkv(const unsigned short* __restrict__ Ho,
                const unsigned short* __restrict__ WOs, const float* __restrict__ BO,
                unsigned short* __restrict__ Xres,
                const float* __restrict__ ln1g, const float* __restrict__ ln1b,
                const unsigned short* __restrict__ W1s, const float* __restrict__ B1,
                const unsigned short* __restrict__ W2s, const float* __restrict__ B2,
                const float* __restrict__ ln2g, const float* __restrict__ ln2b,
                const unsigned short* __restrict__ QKVs, const float* __restrict__ bqkv,
                unsigned short* __restrict__ Qb, unsigned short* __restrict__ Kb,
                unsigned short* __restrict__ Vb) {
    __shared__ __align__(16) unsigned char lds[51200];
    unsigned char* Lo = lds;                 // staging, then FFN hidden
    float* lsum = (float*)(lds + 24576);     // [64][4]
    float* lsq  = lsum + 256;
    unsigned char* Ap = lds + 26624;
    const int tid = threadIdx.x;
    const int lane = tid & 63;
    const int w = tid >> 6;                  // 0..3
    const int m0 = blockIdx.x * 64;
    const int q = lane >> 4, q8 = q << 3, r15 = lane & 15;
    const int nb = w * 48 + r15;

    #pragma unroll
    for (int it = 0; it < 6; ++it) {
        int c = it * 4 + w;                  // 0..23
        int g = c / 6, sk = c - g * 6;
        async_lds16(Ho + (size_t)(m0 + g * 16 + r15) * 192 + sk * 32 + q8, Lo + c * 1024);
    }
    __syncthreads();

    float4v xres[4][3];
    #pragma unroll
    for (int i = 0; i < 4; ++i)
        #pragma unroll
        for (int j = 0; j < 3; ++j)
            xres[i][j] = (float4v){0.f, 0.f, 0.f, 0.f};
    #pragma unroll
    for (int kk = 0; kk < 6; ++kk) {
        short8 af[4], wf[3];
        #pragma unroll
        for (int j = 0; j < 3; ++j)
            wf[j] = *(const short8*)(WOs + (((size_t)(w * 3 + j) * 6 + kk) << 9) + lane * 8);
        #pragma unroll
        for (int i = 0; i < 4; ++i)
            af[i] = *(const short8*)(Lo + ((i * 6 + kk) << 10) + lane * 16);
        #pragma unroll
        for (int i = 0; i < 4; ++i)
            #pragma unroll
            for (int j = 0; j < 3; ++j)
                xres[i][j] = __builtin_amdgcn_mfma_f32_16x16x32_bf16(af[i], wf[j], xres[i][j], 0, 0, 0);
    }
    // residual into registers (vector 8B read; write deferred to after FFN)
    #pragma unroll
    for (int j = 0; j < 3; ++j) {
        int n = nb + j * 16;
        float bv = BO[n];
        #pragma unroll
        for (int i = 0; i < 4; ++i) {
            const unsigned short* xp = Xres + XF(blockIdx.x * 4 + i, n) + q * 4;
            uintx2 u = *(const uintx2*)xp;
            float f[4]; xf_unpack(u, f);
            #pragma unroll
            for (int r = 0; r < 4; ++r) xres[i][j][r] += bv + f[r];
        }
    }
    // LN1 stats + scatter A'
    #pragma unroll
    for (int i = 0; i < 4; ++i)
        #pragma unroll
        for (int r = 0; r < 4; ++r) {
            float s1 = xres[i][0][r] + xres[i][1][r] + xres[i][2][r];
            float s2 = xres[i][0][r] * xres[i][0][r] + xres[i][1][r] * xres[i][1][r] + xres[i][2][r] * xres[i][2][r];
            #pragma unroll
            for (int off = 1; off < 16; off <<= 1) {
                s1 += __shfl_xor(s1, off, 64);
                s2 += __shfl_xor(s2, off, 64);
            }
            if (r15 == 0) {
                int rl = i * 16 + q * 4 + r;
                lsum[rl * 4 + w] = s1;
                lsq[rl * 4 + w] = s2;
            }
        }
    __syncthreads();
    #pragma unroll
    for (int i = 0; i < 4; ++i) {
        float mean[4], rstd[4];
        #pragma unroll
        for (int r = 0; r < 4; ++r) {
            int rl4 = (i * 16 + q * 4 + r) * 4;
            float s  = lsum[rl4] + lsum[rl4 + 1] + lsum[rl4 + 2] + lsum[rl4 + 3];
            float ss = lsq[rl4] + lsq[rl4 + 1] + lsq[rl4 + 2] + lsq[rl4 + 3];
            float m = s * (1.0f / 192.0f);
            mean[r] = m;
            rstd[r] = rsqrtf(ss * (1.0f / 192.0f) - m * m + 1e-5f);
        }
        #pragma unroll
        for (int j = 0; j < 3; ++j) {
            int h = nb + j * 16;
            float gg = ln1g[h], bb = ln1b[h];
            unsigned short* ap = (unsigned short*)Ap + (i * 6 + (h >> 5)) * 512
                               + ((h >> 3) & 3) * 128 + (h & 7) + q * 32;
            float v0 = (xres[i][j][0] - mean[0]) * rstd[0] * gg + bb;
            float v1 = (xres[i][j][1] - mean[1]) * rstd[1] * gg + bb;
            float v2 = (xres[i][j][2] - mean[2]) * rstd[2] * gg + bb;
            float v3 = (xres[i][j][3] - mean[3]) * rstd[3] * gg + bb;
            st2u(ap, ap + 8, v0, v1);
            st2u(ap + 16, ap + 24, v2, v3);
        }
    }
    __syncthreads();

    // FFN: hidden chunks of 192, hidden lives only in LDS (Lo)
    float4v acc2[4][3];
    #pragma unroll
    for (int i = 0; i < 4; ++i)
        #pragma unroll
        for (int j = 0; j < 3; ++j)
            acc2[i][j] = (float4v){0.f, 0.f, 0.f, 0.f};
    for (int hc = 0; hc < 4; ++hc) {
        float4v acc1[4][3];
        #pragma unroll
        for (int i = 0; i < 4; ++i)
            #pragma unroll
            for (int j = 0; j < 3; ++j)
                acc1[i][j] = (float4v){0.f, 0.f, 0.f, 0.f};
        #pragma unroll
        for (int kk = 0; kk < 6; ++kk) {
            short8 af[4], wf[3];
            #pragma unroll
            for (int j = 0; j < 3; ++j)
                wf[j] = *(const short8*)(W1s + (((size_t)(hc * 12 + w * 3 + j) * 6 + kk) << 9) + lane * 8);
            #pragma unroll
            for (int i = 0; i < 4; ++i)
                af[i] = *(const short8*)(Ap + ((i * 6 + kk) << 10) + lane * 16);
            #pragma unroll
            for (int i = 0; i < 4; ++i)
                #pragma unroll
                for (int j = 0; j < 3; ++j)
                    acc1[i][j] = __builtin_amdgcn_mfma_f32_16x16x32_bf16(af[i], wf[j], acc1[i][j], 0, 0, 0);
        }
        __syncthreads();
        #pragma unroll
        for (int i = 0; i < 4; ++i)
            #pragma unroll
            for (int j = 0; j < 3; ++j) {
                int h = nb + j * 16;
                float bv = B1[hc * 192 + h];
                unsigned short* lp = (unsigned short*)Lo + (i * 6 + (h >> 5)) * 512
                                   + ((h >> 3) & 3) * 128 + (h & 7) + q * 32;
                float v0 = gelu_f(acc1[i][j][0] + bv);
                float v1 = gelu_f(acc1[i][j][1] + bv);
                float v2 = gelu_f(acc1[i][j][2] + bv);
                float v3 = gelu_f(acc1[i][j][3] + bv);
                st2u(lp, lp + 8, v0, v1);
                st2u(lp + 16, lp + 24, v2, v3);
            }
        __syncthreads();
        #pragma unroll
        for (int kk = 0; kk < 6; ++kk) {
            short8 af[4], wf[3];
            #pragma unroll
            for (int j = 0; j < 3; ++j)
                wf[j] = *(const short8*)(W2s + (((size_t)(w * 3 + j) * 24 + hc * 6 + kk) << 9) + lane * 8);
            #pragma unroll
            for (int i = 0; i < 4; ++i)
                af[i] = *(const short8*)(Lo + ((i * 6 + kk) << 10) + lane * 16);
            #pragma unroll
            for (int i = 0; i < 4; ++i)
                #pragma unroll
                for (int j = 0; j < 3; ++j)
                    acc2[i][j] = __builtin_amdgcn_mfma_f32_16x16x32_bf16(af[i], wf[j], acc2[i][j], 0, 0, 0);
        }
    }

    // FFN residual; single vector X write (packed bf16)
    #pragma unroll
    for (int j = 0; j < 3; ++j) {
        int n = nb + j * 16;
        float bv = B2[n];
        #pragma unroll
        for (int i = 0; i < 4; ++i) {
            #pragma unroll
            for (int r = 0; r < 4; ++r)
                xres[i][j][r] += acc2[i][j][r] + bv;
            unsigned short* xp = Xres + XF(blockIdx.x * 4 + i, n) + q * 4;
            uintx2 o;
            o[0] = cvt_pk_bf16(xres[i][j][0], xres[i][j][1]);
            o[1] = cvt_pk_bf16(xres[i][j][2], xres[i][j][3]);
            *(uintx2*)xp = o;
        }
    }
    if (LASTB) return;

    // LN2 + next-block QKV
    #pragma unroll
    for (int i = 0; i < 4; ++i)
        #pragma unroll
        for (int r = 0; r < 4; ++r) {
            float s1 = xres[i][0][r] + xres[i][1][r] + xres[i][2][r];
            float s2 = xres[i][0][r] * xres[i][0][r] + xres[i][1][r] * xres[i][1][r] + xres[i][2][r] * xres[i][2][r];
            #pragma unroll
            for (int off = 1; off < 16; off <<= 1) {
                s1 += __shfl_xor(s1, off, 64);
                s2 += __shfl_xor(s2, off, 64);
            }
            if (r15 == 0) {
                int rl = i * 16 + q * 4 + r;
                lsum[rl * 4 + w] = s1;
                lsq[rl * 4 + w] = s2;
            }
        }
    __syncthreads();
    #pragma unroll
    for (int i = 0; i < 4; ++i) {
        float mean[4], rstd[4];
        #pragma unroll
        for (int r = 0; r < 4; ++r) {
            int rl4 = (i * 16 + q * 4 + r) * 4;
            float s  = lsum[rl4] + lsum[rl4 + 1] + lsum[rl4 + 2] + lsum[rl4 + 3];
            float ss = lsq[rl4] + lsq[rl4 + 1] + lsq[rl4 + 2] + lsq[rl4 + 3];
            float m = s * (1.0f / 192.0f);
            mean[r] = m;
            rstd[r] = rsqrtf(ss * (1.0f / 192.0f) - m * m + 1e-5f);
        }
        #pragma unroll
        for (int j = 0; j < 3; ++j) {
            int h = nb + j * 16;
            float gg = ln2g[h], bb = ln2b[h];
            unsigned short* ap = (unsigned short*)Ap + (i * 6 + (h >> 5)) * 512
                               + ((h >> 3) & 3) * 128 + (h & 7) + q * 32;
            float v0 = (xres[i][j][0] - mean[0]) * rstd[0] * gg + bb;
            float v1 = (xres[i][j][1] - mean[1]) * rstd[1] * gg + bb;
            float v2 = (xres[i][j][2] - mean[2]) * rstd[2] * gg + bb;
            float v3 = (xres[i][j][3] - mean[3]) * rstd[3] * gg + bb;
            st2u(ap, ap + 8, v0, v1);
            st2u(ap + 16, ap + 24, v2, v3);
        }
    }
    __syncthreads();

    // next-block QKV: direct global stores
    for (int seg = 0; seg < 3; ++seg) {
        float4v a2[4][3];
        #pragma unroll
        for (int i = 0; i < 4; ++i)
            #pragma unroll
            for (int j = 0; j < 3; ++j)
                a2[i][j] = (float4v){0.f, 0.f, 0.f, 0.f};
        #pragma unroll
        for (int kk = 0; kk < 6; ++kk) {
            short8 af[4], wf[3];
            #pragma unroll
            for (int j = 0; j < 3; ++j)
                wf[j] = *(const short8*)(QKVs + (((size_t)(seg * 12 + w * 3 + j) * 6 + kk) << 9) + lane * 8);
            #pragma unroll
            for (int i = 0; i < 4; ++i)
                af[i] = *(const short8*)(Ap + ((i * 6 + kk) << 10) + lane * 16);
            #pragma unroll
            for (int i = 0; i < 4; ++i)
                #pragma unroll
                for (int j = 0; j < 3; ++j)
                    a2[i][j] = __builtin_amdgcn_mfma_f32_16x16x32_bf16(af[i], wf[j], a2[i][j], 0, 0, 0);
        }
        unsigned short* dst = (seg == 0) ? Qb : (seg == 1) ? Kb : Vb;
        #pragma unroll
        for (int j = 0; j < 3; ++j) {
            int n = nb + j * 16;
            float bv = bqkv[seg * 192 + n];
            #pragma unroll
            for (int i = 0; i < 4; ++i) {
                int mrow = m0 + i * 16 + q * 4;
                #pragma unroll
                for (int r = 0; r < 4; ++r) {
                    float x = a2[i][j][r] + bv;
                    if (seg < 2) x = (x > 0.f) ? x + 1.f : __expf(x);
                    if (seg == 0) x *= 0.14433756729740643f;
                    dst[(size_t)(mrow + r) * 192 + n] = f2b(x);
                }
            }
        }
    }
}

// ---------------- ROW attention: one block per (row-group, head) ----------------
__global__ __launch_bounds__(256) void attn_rowh(const unsigned short* __restrict__ Qb,
                                                 const unsigned short* __restrict__ Kb,
                                                 const unsigned short* __restrict__ Vb,
                                                 unsigned short* __restrict__ O) {
    __shared__ __align__(16) unsigned char lds[58368];
    unsigned char* stg = lds;                              // [256 rows][208 B] K|V swizzled
    float* pub = (float*)lds;                              // [4][48][64] f32 (aliases stg)
    unsigned short* kvs = (unsigned short*)(lds + 49152);  // [64][72] shorts
    const int tid = threadIdx.x;
    const int lane = tid & 63;
    const int wq = tid >> 6;                 // ks quarter 0..3
    const int h = blockIdx.x & 3;
    const size_t base = (size_t)(blockIdx.x >> 2) * 256;
    const int q = lane >> 4, r15 = lane & 15, q8 = q * 8;

    // stage: 256 rows x (48K + 48V) shorts, row stride 208B, XOR ((row>>3)&3)<<5
    short8 rg[12];
    #pragma unroll
    for (int it = 0; it < 12; ++it) {
        int u = it * 256 + tid;
        int row = u / 12, c8 = u - (u / 12) * 12;
        const unsigned short* gp = (c8 < 6)
            ? (Kb + (base + row) * 192 + h * 48 + c8 * 8)
            : (Vb + (base + row) * 192 + h * 48 + (c8 - 6) * 8);
        rg[it] = *(const short8*)gp;
    }
    #pragma unroll
    for (int it = 0; it < 12; ++it) {
        int u = it * 256 + tid;
        int row = u / 12, c8 = u - (u / 12) * 12;
        int ba = (row * 208 + c8 * 16) ^ (((row >> 3) & 3) << 5);
        *(short8*)(stg + ba) = rg[it];
    }
    __syncthreads();

    short8 onesf;
    #pragma unroll
    for (int e = 0; e < 8; ++e) onesf[e] = (short)0x3F80;

    float4v kv[3][4];
    #pragma unroll
    for (int i = 0; i < 3; ++i)
        #pragma unroll
        for (int j = 0; j < 4; ++j)
            kv[i][j] = (float4v){0.f, 0.f, 0.f, 0.f};

    #pragma unroll
    for (int sc = 0; sc < 2; ++sc) {
        int ks0 = wq * 64 + sc * 32;
        short8 af[3], bf[3];
        #pragma unroll
        for (int t = 0; t < 3; ++t) {
            #pragma unroll
            for (int j = 0; j < 8; ++j) {
                int row = ks0 + q8 + j;
                int sw = ((row >> 3) & 3) << 5;
                af[t][j] = *(const short*)(stg + ((row * 208 + (t * 16 + r15) * 2) ^ sw));
                bf[t][j] = *(const short*)(stg + ((row * 208 + 96 + (t * 16 + r15) * 2) ^ sw));
            }
        }
        #pragma unroll
        for (int i = 0; i < 3; ++i) {
            #pragma unroll
            for (int j = 0; j < 3; ++j)
                kv[i][j] = __builtin_amdgcn_mfma_f32_16x16x32_bf16(af[i], bf[j], kv[i][j], 0, 0, 0);
            kv[i][3] = __builtin_amdgcn_mfma_f32_16x16x32_bf16(af[i], onesf, kv[i][3], 0, 0, 0);
        }
    }
    __syncthreads();                         // staging reads done; pub/kvs may reuse space

    // publish partial KV states (f32)
    {
        float* kp = pub + wq * 3072;
        #pragma unroll
        for (int i = 0; i < 3; ++i)
            #pragma unroll
            for (int j = 0; j < 4; ++j)
                #pragma unroll
                for (int r = 0; r < 4; ++r)
                    kp[((i * 4 + j) * 4 + r) * 64 + lane] = kv[i][j][r];
    }
    __syncthreads();

    // zero kvs cols 48..63 (k_ch beyond 47 must be 0 for kk=1 fragments)
    {
        unsigned int* kz = (unsigned int*)kvs;
        #pragma unroll
        for (int z = 0; z < 2; ++z) {
            int zz = z * 256 + tid;
            int zr = zz >> 3, zc = zz & 7;
            kz[zr * 36 + 24 + zc] = 0;
        }
    }
    // combine: wave wq sums V-block j==wq across 4 partials, emits kvs rows
    #pragma unroll
    for (int i = 0; i < 3; ++i)
        #pragma unroll
        for (int r = 0; r < 4; ++r) {
            int idx = ((i * 4 + wq) * 4 + r) * 64 + lane;
            float s = pub[idx] + pub[3072 + idx] + pub[6144 + idx] + pub[9216 + idx];
            int kc = i * 16 + q * 4 + r;
            if (wq < 3)
                kvs[(wq * 16 + r15) * 72 + kc] = f2b(s);
            else
                kvs[(48 + r15) * 72 + kc] = (r15 == 0) ? f2b(s) : (unsigned short)0;
        }
    __syncthreads();

    short8 bkv[2][4];
    #pragma unroll
    for (int kk = 0; kk < 2; ++kk)
        #pragma unroll
        for (int t = 0; t < 4; ++t)
            bkv[kk][t] = *(const short8*)&kvs[(t * 16 + r15) * 72 + kk * 32 + q8];

    #pragma unroll
    for (int m = 0; m < 4; ++m) {
        int mt = wq * 4 + m;
        float4v o[4];
        #pragma unroll
        for (int t = 0; t < 4; ++t) o[t] = (float4v){0.f, 0.f, 0.f, 0.f};
        #pragma unroll
        for (int kk = 0; kk < 2; ++kk) {
            const unsigned short* qp = Qb + (base + (size_t)(mt * 16 + r15)) * 192
                                       + h * 48 + kk * 32 + q8;
            short8 aq = *(const short8*)qp;
            #pragma unroll
            for (int t = 0; t < 4; ++t)
                o[t] = __builtin_amdgcn_mfma_f32_16x16x32_bf16(aq, bkv[kk][t], o[t], 0, 0, 0);
        }
        #pragma unroll
        for (int r = 0; r < 4; ++r) {
            float den = __shfl(o[3][r], q << 4);
            float z = 1.0f / (den + 1e-6f);
            int n = mt * 16 + q * 4 + r;
            unsigned short* op = O + (base + (size_t)n) * 192 + h * 48;
            #pragma unroll
            for (int t = 0; t < 3; ++t)
                op[t * 16 + r15] = f2b(o[t][r] * z);
        }
    }
}

// ---------------- COL attention (pixel-major K/V, swizzled LDS gather) ----------------
template<int N, int MSTR>
__global__ __launch_bounds__(256) void attn_axial(const unsigned short* __restrict__ Qb,
                                                  const unsigned short* __restrict__ Kb,
                                                  const unsigned short* __restrict__ Vb,
                                                  unsigned short* __restrict__ O) {
    __shared__ unsigned short KV[32][400];
    __shared__ unsigned short kvs[4][64][72];
    unsigned char* kvb = (unsigned char*)KV;
    const int tid = threadIdx.x;
    const int lane = tid & 63;
    const int w = tid >> 6;
    const int q = lane >> 4, r15 = lane & 15, q8 = q * 8;
    size_t base;
    if (MSTR == 1) base = (size_t)blockIdx.x * N;
    else           base = (size_t)(blockIdx.x >> 8) * 16384 + (blockIdx.x & 255);

    unsigned int* kz = (unsigned int*)&kvs[w][0][0];
    #pragma unroll
    for (int ii = 0; ii < 36; ++ii) kz[lane + ii * 64] = 0;

    short8 onesf;
    #pragma unroll
    for (int e = 0; e < 8; ++e) onesf[e] = (short)0x3F80;

    float4v kv[3][4];
    #pragma unroll
    for (int i = 0; i < 3; ++i)
        #pragma unroll
        for (int j = 0; j < 4; ++j)
            kv[i][j] = (float4v){0.f, 0.f, 0.f, 0.f};

    for (int ks = 0; ks < N; ks += 32) {
        #pragma unroll
        for (int it = 0; it < 6; ++it) {
            int cc = tid + it * 256;
            int row = cc / 48, c8 = cc - (cc / 48) * 48;
            size_t poff = (base + (size_t)(ks + row) * MSTR) * 192;
            const unsigned short* gp = (c8 < 24) ? (Kb + poff + c8 * 8) : (Vb + poff + (c8 - 24) * 8);
            int ba = (row * 800 + c8 * 16) ^ (((row >> 3) & 3) << 5);
            *(short8*)(kvb + ba) = *(const short8*)gp;
        }
        __syncthreads();
        short8 af[3], bf[3];
        #pragma unroll
        for (int t = 0; t < 3; ++t) {
            #pragma unroll
            for (int j = 0; j < 8; ++j) {
                int row = q8 + j;
                int sw = ((row >> 3) & 3) << 5;
                af[t][j] = *(short*)(kvb + ((row * 800 + (w * 48 + t * 16 + r15) * 2) ^ sw));
                bf[t][j] = *(short*)(kvb + ((row * 800 + 384 + (w * 48 + t * 16 + r15) * 2) ^ sw));
            }
        }
        #pragma unroll
        for (int i = 0; i < 3; ++i) {
            #pragma unroll
            for (int j = 0; j < 3; ++j)
                kv[i][j] = __builtin_amdgcn_mfma_f32_16x16x32_bf16(af[i], bf[j], kv[i][j], 0, 0, 0);
            kv[i][3] = __builtin_amdgcn_mfma_f32_16x16x32_bf16(af[i], onesf, kv[i][3], 0, 0, 0);
        }
        __syncthreads();
    }

    #pragma unroll
    for (int i = 0; i < 3; ++i) {
        #pragma unroll
        for (int j = 0; j < 3; ++j)
            #pragma unroll
            for (int r = 0; r < 4; ++r)
                kvs[w][j * 16 + r15][i * 16 + q * 4 + r] = f2b(kv[i][j][r]);
        if (r15 == 0)
            #pragma unroll
            for (int r = 0; r < 4; ++r)
                kvs[w][48][i * 16 + q * 4 + r] = f2b(kv[i][3][r]);
    }

    short8 bkv[2][4];
    #pragma unroll
    for (int kk = 0; kk < 2; ++kk)
        #pragma unroll
        for (int t = 0; t < 4; ++t)
            bkv[kk][t] = *(const short8*)&kvs[w][t * 16 + r15][kk * 32 + q8];

    for (int mt = 0; mt < N / 16; ++mt) {
        float4v o[4];
        #pragma unroll
        for (int t = 0; t < 4; ++t) o[t] = (float4v){0.f, 0.f, 0.f, 0.f};
        #pragma unroll
        for (int kk = 0; kk < 2; ++kk) {
            const unsigned short* qp = Qb + (base + (size_t)(mt * 16 + r15) * MSTR) * 192
                                       + w * 48 + kk * 32 + q8;
            short8 aq = *(const short8*)qp;
            #pragma unroll
            for (int t = 0; t < 4; ++t)
                o[t] = __builtin_amdgcn_mfma_f32_16x16x32_bf16(aq, bkv[kk][t], o[t], 0, 0, 0);
        }
        #pragma unroll
        for (int r = 0; r < 4; ++r) {
            float den = __shfl(o[3][r], q << 4);
            float z = 1.0f / (den + 1e-6f);
            int n = mt * 16 + q * 4 + r;
            unsigned short* op = O + (base + (size_t)n * MSTR) * 192 + w * 48;
            #pragma unroll
            for (int t = 0; t < 3; ++t)
                op[t * 16 + r15] = f2b(o[t][r] * z);
        }
    }
}

__global__ __launch_bounds__(256) void final_kernel(const unsigned short* __restrict__ X,
                                                    const float* __restrict__ pw_w,
                                                    const float* __restrict__ pw_b, float* __restrict__ out) {
    int wave = threadIdx.x >> 6;
    int lane = threadIdx.x & 63;
    int p = blockIdx.x * 4 + wave;
    const unsigned short* xp = X + XF(p >> 4, 0) + (p & 15);
    float s = b2f(xp[(size_t)lane << 4]) * pw_w[lane]
            + b2f(xp[(size_t)(lane + 64) << 4]) * pw_w[lane + 64]
            + b2f(xp[(size_t)(lane + 128) << 4]) * pw_w[lane + 128];
    #pragma unroll
    for (int off = 32; off; off >>= 1) s += __shfl_xor(s, off, 64);
    if (lane == 0) {
        float o = s + pw_b[0];
        float e = expf(o);
        out[p] = 1.0f - 1.0f / (2.0f + e);
    }
}

extern "C" void kernel_launch(void* const* d_in, const int* in_sizes, int n_in,
                              void* d_out, int out_size, void* d_ws, size_t ws_size,
                              hipStream_t stream) {
    const int*   tokens = (const int*)  d_in[0];
    const float* emb    = (const float*)d_in[1];
    const float* proj_w = (const float*)d_in[2];
    const float* proj_b = (const float*)d_in[3];
    const float* ln_g   = (const float*)d_in[4];
    const float* ln_b   = (const float*)d_in[5];
    const float* wq     = (const float*)d_in[6];
    const float* wk     = (const float*)d_in[7];
    const float* wv     = (const float*)d_in[8];
    const float* wo     = (const float*)d_in[9];
    const float* bq     = (const float*)d_in[10];
    const float* bk     = (const float*)d_in[11];
    const float* bv     = (const float*)d_in[12];
    const float* bo     = (const float*)d_in[13];
    const float* ffn_w1 = (const float*)d_in[14];
    const float* ffn_b1 = (const float*)d_in[15];
    const float* ffn_w2 = (const float*)d_in[16];
    const float* ffn_b2 = (const float*)d_in[17];
    const float* pw_w   = (const float*)d_in[18];
    const float* pw_b   = (const float*)d_in[19];

    unsigned short* X    = (unsigned short*)d_ws;        // bf16 residual stream (fragment-major)
    unsigned short* Ho   = X + BUF;
    unsigned short* Qb   = Ho + BUF;
    unsigned short* Kb   = Qb + BUF;
    unsigned short* Vb   = Kb + BUF;
    unsigned short* Eg   = Vb + BUF;                     // NP*64
    unsigned short* wqkvb = Eg + (size_t)NP * 64;
    const int QKVSZ = NBLK * 2 * 576 * CCH;
    const int WSZ   = NBLK * 2 * CCH * CCH;
    const int FSZ   = NBLK * 768 * CCH;
    unsigned short* wob = wqkvb + QKVSZ;
    unsigned short* w1b = wob + WSZ;
    unsigned short* w2b = w1b + FSZ;
    unsigned short* pjb = w2b + FSZ;                     // 12288
    float* bqkvb = (float*)(pjb + 12288 + 32);
    float* Xt = (float*)Qb;                              // proj tmp fp32 (spans Qb+Kb, free pre-loop)

    wqkv_swz<<<QKVSZ / 256, 256, 0, stream>>>(wq, wk, wv, wqkvb);
    bqkv_concat<<<27, 256, 0, stream>>>(bq, bk, bv, bqkvb);
    swz_conv<192, 192><<<(WSZ + 255) / 256, 256, 0, stream>>>(wo, wob, NBLK * 2);
    swz_conv<768, 192><<<(FSZ + 255) / 256, 256, 0, stream>>>(ffn_w1, w1b, NBLK);
    swz_conv<192, 768><<<(FSZ + 255) / 256, 256, 0, stream>>>(ffn_w2, w2b, NBLK);
    swz_conv<192, 64><<<48, 256, 0, stream>>>(proj_w, pjb, 1);

    gather_kernel<<<NP * 64 / 256, 256, 0, stream>>>(tokens, emb, Eg);
    mm192<64, 1><<<dim3(1, NP / 64), 256, 0, stream>>>(Eg, pjb, proj_b,
                                                       nullptr, nullptr, nullptr, Xt, NP, CCH, 64);
    rotary_ln_kernel<<<NP / 4, 256, 0, stream>>>(Xt, X, Ho, ln_g, ln_b);
    mm192<128, 0><<<dim3(3, NP / 128), 256, 0, stream>>>(Ho, wqkvb, bqkvb,
                                                         Qb, Kb, Vb, nullptr, NP, 576, CCH);

    for (int i = 0; i < NBLK; ++i) {
        size_t wi0 = (size_t)(i * 2), wi1 = wi0 + 1;
        attn_rowh<<<BB * SS * 4, 256, 0, stream>>>(Qb, Kb, Vb, Ho);
        wo_qkv<<<NP / 32, 256, 0, stream>>>(Ho, wob + wi0 * CCH * CCH, bo + wi0 * CCH, X,
                                            ln_g + (size_t)(i * 3 + 1) * CCH, ln_b + (size_t)(i * 3 + 1) * CCH,
                                            wqkvb + wi1 * 576 * CCH, bqkvb + wi1 * 576, Qb, Kb, Vb);
        attn_axial<SS, LL><<<BB * LL, 256, 0, stream>>>(Qb, Kb, Vb, Ho);
        if (i < NBLK - 1) {
            size_t wn0 = (size_t)((i + 1) * 2);
            wo_ffn_qkv<false><<<NP / 64, 256, 0, stream>>>(
                Ho, wob + wi1 * CCH * CCH, bo + wi1 * CCH, X,
                ln_g + (size_t)(i * 3 + 2) * CCH, ln_b + (size_t)(i * 3 + 2) * CCH,
                w1b + (size_t)i * 768 * CCH, ffn_b1 + (size_t)i * 768,
                w2b + (size_t)i * CCH * 768, ffn_b2 + (size_t)i * CCH,
                ln_g + (size_t)((i + 1) * 3) * CCH, ln_b + (size_t)((i + 1) * 3) * CCH,
                wqkvb + wn0 * 576 * CCH, bqkvb + wn0 * 576, Qb, Kb, Vb);
        } else {
            wo_ffn_qkv<true><<<NP / 64, 256, 0, stream>>>(
                Ho, wob + wi1 * CCH * CCH, bo + wi1 * CCH, X,
                ln_g + (size_t)(i * 3 + 2) * CCH, ln_b + (size_t)(i * 3 + 2) * CCH,
                w1b + (size_t)i * 768 * CCH, ffn_b1 + (size_t)i * 768,
                w2b + (size_t)i * CCH * 768, ffn_b2 + (size_t)i * CCH,
                nullptr, nullptr, nullptr, nullptr, nullptr, nullptr, nullptr);
        }
    }
    final_kernel<<<NP / 4, 256, 0, stream>>>(X, pw_w, pw_b, (float*)d_out);
}

// Round 14
// 833.597 us; speedup vs baseline: 1.3988x; 1.0247x over previous
//
#include <hip/hip_runtime.h>
#include <hip/hip_bf16.h>
#include <math.h>

#define NBLK 6
#define NH 4
#define CCH 192
#define BB 2
#define SS 64
#define LL 256
#define DH 48
#define NP (BB*SS*LL)            // 32768 pixels
#define BUF ((size_t)NP*CCH)

typedef __attribute__((ext_vector_type(8))) short short8;
typedef __attribute__((ext_vector_type(4))) float float4v;
typedef __attribute__((ext_vector_type(2))) unsigned int uintx2;

__device__ __forceinline__ unsigned short f2b(float f) {
    union { float f; unsigned int u; } v; v.f = f;
    unsigned int r = v.u + 0x7FFF + ((v.u >> 16) & 1);
    return (unsigned short)(r >> 16);
}
__device__ __forceinline__ float b2f(unsigned short u) {
    union { unsigned int u; float f; } v; v.u = ((unsigned int)u) << 16;
    return v.f;
}
// packed f32x2 -> bf16x2 (RNE)
__device__ __forceinline__ unsigned int cvt_pk_bf16(float lo, float hi) {
    unsigned int r;
    asm("v_cvt_pk_bf16_f32 %0, %1, %2" : "=v"(r) : "v"(lo), "v"(hi));
    return r;
}
__device__ __forceinline__ void st2u(unsigned short* p0, unsigned short* p1, float a, float b) {
    unsigned int u = cvt_pk_bf16(a, b);
    *p0 = (unsigned short)u;
    *p1 = (unsigned short)(u >> 16);
}
__device__ __forceinline__ void xf_unpack(uintx2 u, float* f) {
    union { unsigned int x; float ff; } t;
    t.x = u[0] << 16;          f[0] = t.ff;
    t.x = u[0] & 0xffff0000u;  f[1] = t.ff;
    t.x = u[1] << 16;          f[2] = t.ff;
    t.x = u[1] & 0xffff0000u;  f[3] = t.ff;
}
// exact-GELU via branch-free A&S 7.1.26 erf (|err| <= 1.5e-7)
__device__ __forceinline__ float gelu_f(float v) {
    float z = v * 0.7071067811865475f;
    float a = fabsf(z);
    float t = __builtin_amdgcn_rcpf(fmaf(0.3275911f, a, 1.0f));
    float p = fmaf(t, 1.061405429f, -1.453152027f);
    p = fmaf(t, p, 1.421413741f);
    p = fmaf(t, p, -0.284496736f);
    p = fmaf(t, p, 0.254829592f);
    p *= t;
    float e = __expf(-a * a);
    float er = fmaf(-p, e, 1.0f);
    er = __builtin_copysignf(er, z);
    return 0.5f * v * (1.0f + er);
}
__device__ __forceinline__ void async_lds16(const void* g, void* l) {
    __builtin_amdgcn_global_load_lds(
        (const __attribute__((address_space(1))) unsigned int*)g,
        (__attribute__((address_space(3))) unsigned int*)l, 16, 0, 0);
}

// fragment-major residual layout: element (p,c) lives at ((p>>4)*192 + c)*16 + (p&15)
#define XF(p16, c) (((size_t)(p16) * 192 + (c)) << 4)

// ---------- fused weight prep: all swizzles + bias concat + gather in ONE launch ----------
// Segment sizes (all multiples of 256 -> no intra-block divergence):
//  [0,A): wqkv swz           A = 12*576*192 = 1327104
//  [A,B): wo  swz (192x192)  B = A + 442368
//  [B,C): w1  swz (768x192)  C = B + 884736
//  [C,D): w2  swz (192x768)  D = C + 884736
//  [D,E): proj swz (192x64)  E = D + 12288
//  [E,F): bqkv concat        F = E + 6912
//  [F,G): gather             G = F + NP*64 = F + 2097152
#define SEG_A 1327104
#define SEG_B (SEG_A + 442368)
#define SEG_C (SEG_B + 884736)
#define SEG_D (SEG_C + 884736)
#define SEG_E (SEG_D + 12288)
#define SEG_F (SEG_E + 6912)
#define SEG_G (SEG_F + NP * 64)

template<int N, int K>
__device__ __forceinline__ void swz_do(const float* __restrict__ src,
                                       unsigned short* __restrict__ dst, int s) {
    constexpr int KC = K / 32;
    int li = s / (N * K);
    int t = s - li * (N * K);
    int chunk = t >> 9, c = t & 511;
    int g = chunk / KC, sk = chunk - g * KC;
    int lane = c >> 3, ko = c & 7;
    int n = g * 16 + (lane & 15), k = sk * 32 + (lane >> 4) * 8 + ko;
    dst[s] = f2b(src[(size_t)li * N * K + (size_t)n * K + k]);
}

__global__ __launch_bounds__(256) void prep_all(
        const float* __restrict__ wq, const float* __restrict__ wk,
        const float* __restrict__ wv, const float* __restrict__ wo,
        const float* __restrict__ f1, const float* __restrict__ f2,
        const float* __restrict__ pj,
        const float* __restrict__ bq, const float* __restrict__ bk,
        const float* __restrict__ bv,
        const int* __restrict__ tokens, const float* __restrict__ emb,
        unsigned short* __restrict__ wqkvb, unsigned short* __restrict__ wob,
        unsigned short* __restrict__ w1b, unsigned short* __restrict__ w2b,
        unsigned short* __restrict__ pjb, float* __restrict__ bqkvb,
        unsigned short* __restrict__ Eg) {
    int s = blockIdx.x * 256 + threadIdx.x;
    if (s < SEG_A) {
        // wqkv swizzle (576x192, 12 layers)
        int wi = s / (576 * 192);
        int t = s - wi * 576 * 192;
        int chunk = t >> 9, c = t & 511;
        int g = chunk / 6, sk = chunk - g * 6;
        int lane = c >> 3, ko = c & 7;
        int n = g * 16 + (lane & 15), k = sk * 32 + (lane >> 4) * 8 + ko;
        int sg = n / 192, row = n - sg * 192;
        const float* src = (sg == 0) ? wq : (sg == 1) ? wk : wv;
        wqkvb[s] = f2b(src[(size_t)wi * 192 * 192 + (size_t)row * 192 + k]);
    } else if (s < SEG_B) {
        swz_do<192, 192>(wo, wob, s - SEG_A);
    } else if (s < SEG_C) {
        swz_do<768, 192>(f1, w1b, s - SEG_B);
    } else if (s < SEG_D) {
        swz_do<192, 768>(f2, w2b, s - SEG_C);
    } else if (s < SEG_E) {
        swz_do<192, 64>(pj, pjb, s - SEG_D);
    } else if (s < SEG_F) {
        int idx = s - SEG_E;                 // 12*576
        int wi = idx / 576, n = idx - wi * 576;
        int sg = n / 192, row = n - sg * 192;
        const float* src = (sg == 0) ? bq : (sg == 1) ? bk : bv;
        bqkvb[idx] = src[wi * CCH + row];
    } else {
        int idx = s - SEG_F;                 // NP*64
        int p = idx >> 6, c = idx & 63;
        Eg[idx] = f2b(emb[tokens[p] * 64 + c]);
    }
}

// rotary + first LayerNorm fused; X stored bf16 fragment-major (storage only — math fp32)
__global__ __launch_bounds__(256) void rotary_ln_kernel(const float* __restrict__ Xt,
                                                        unsigned short* __restrict__ X,
                                                        unsigned short* __restrict__ Hn,
                                                        const float* __restrict__ g, const float* __restrict__ b) {
    int wave = threadIdx.x >> 6;
    int lane = threadIdx.x & 63;
    int p = blockIdx.x * 4 + wave;
    int l = p & (LL - 1);
    const float* xp = Xt + (size_t)p * CCH;
    float v[3];
    #pragma unroll
    for (int i = 0; i < 3; ++i) {
        int c = lane + i * 64;
        int j = c % 96;
        float inv = expf((float)(2 * j) * (-9.210340371976184f / 192.0f));
        float ang = (float)l * inv;
        float part = (c < 96) ? -xp[c + 96] : xp[c - 96];
        v[i] = xp[c] * cosf(ang) + part * sinf(ang);
    }
    float s = v[0] + v[1] + v[2];
    float qq = v[0] * v[0] + v[1] * v[1] + v[2] * v[2];
    #pragma unroll
    for (int off = 32; off; off >>= 1) {
        s += __shfl_xor(s, off, 64);
        qq += __shfl_xor(qq, off, 64);
    }
    float mean = s * (1.0f / 192.0f);
    float var = qq * (1.0f / 192.0f) - mean * mean;
    float r = rsqrtf(var + 1e-5f);
    unsigned short* hp = Hn + (size_t)p * CCH;
    const int p16 = p >> 4, pr = p & 15;
    #pragma unroll
    for (int i = 0; i < 3; ++i) {
        int c = lane + i * 64;
        X[XF(p16, c) + pr] = f2b(v[i]);
        hp[c] = f2b((v[i] - mean) * r * g[c] + b[c]);
    }
}

// ---------------- bf16 MFMA GEMM (pre-loop only: proj, block-0 QKV) ----------------
template<int MT, int EPI>
__global__ __launch_bounds__(256, (MT == 128) ? 3 : 4)
void mm192(const unsigned short* __restrict__ A, const unsigned short* __restrict__ Wsw,
           const float* __restrict__ bias,
           unsigned short* __restrict__ O0, unsigned short* __restrict__ O1,
           unsigned short* __restrict__ O2,
           float* __restrict__ Of,
           int M, int N, int K) {
    constexpr int NI = MT / 32;
    __shared__ __align__(16) unsigned char lds[(MT == 128) ? 51200 : 28672];
    const int tid = threadIdx.x;
    const int lane = tid & 63;
    const int w = tid >> 6;
    const int wm = w >> 1, wn = w & 1;
    const int m0 = blockIdx.y * MT;
    const int g0 = blockIdx.x * 12;
    const int q = lane >> 4;
    const int q8 = q << 3;
    const int r15 = lane & 15;
    const int KC = K >> 5;

    for (int c = w; c < (MT / 16) * KC; c += 4) {
        int g = c / KC, sk = c - g * KC;
        async_lds16(A + (size_t)(m0 + g * 16 + r15) * K + sk * 32 + q8, lds + c * 1024);
    }

    float4v acc[NI][6];
    #pragma unroll
    for (int i = 0; i < NI; ++i)
        #pragma unroll
        for (int j = 0; j < 6; ++j)
            acc[i][j] = (float4v){0.f, 0.f, 0.f, 0.f};

    __syncthreads();

    for (int sk = 0; sk < KC; ++sk) {
        short8 af[NI], wf[6];
        #pragma unroll
        for (int j = 0; j < 6; ++j)
            wf[j] = *(const short8*)(Wsw + (((size_t)(g0 + wn * 6 + j) * KC + sk) << 9) + lane * 8);
        #pragma unroll
        for (int i = 0; i < NI; ++i)
            af[i] = *(const short8*)(lds + (((wm * NI + i) * KC + sk) << 10) + lane * 16);
        #pragma unroll
        for (int i = 0; i < NI; ++i)
            #pragma unroll
            for (int j = 0; j < 6; ++j)
                acc[i][j] = __builtin_amdgcn_mfma_f32_16x16x32_bf16(af[i], wf[j], acc[i][j], 0, 0, 0);
    }

    const int nb = blockIdx.x * 192 + wn * 96 + r15;
    const int mb = m0 + wm * (MT / 2) + q * 4;

    if (EPI == 0) {
        const int bx = blockIdx.x;
        unsigned short* dst = (bx == 0) ? O0 : (bx == 1) ? O1 : O2;
        #pragma unroll
        for (int j = 0; j < 6; ++j) {
            int n = nb + j * 16;                      // global 576-wide col (bias)
            int col = wn * 96 + j * 16 + r15;         // local 192-wide col (store)
            float bv = bias[n];
            #pragma unroll
            for (int i = 0; i < NI; ++i) {
                int mrow = wm * (MT / 2) + i * 16 + q * 4;
                #pragma unroll
                for (int r = 0; r < 4; ++r) {
                    float v = acc[i][j][r] + bv;
                    if (bx < 2) v = (v > 0.f) ? v + 1.f : __expf(v);
                    if (bx == 0) v *= 0.14433756729740643f;
                    dst[(size_t)(m0 + mrow + r) * 192 + col] = f2b(v);
                }
            }
        }
    } else {
        #pragma unroll
        for (int j = 0; j < 6; ++j) {
            int n = nb + j * 16;
            float bv = bias[n];
            #pragma unroll
            for (int i = 0; i < NI; ++i) {
                int mrow = mb + i * 16;
                #pragma unroll
                for (int r = 0; r < 4; ++r)
                    Of[(size_t)(mrow + r) * N + n] = acc[i][j][r] + bv;
            }
        }
    }
}

// ======== fused per-pixel GEMM chains ========

// ---- WO + residual + LN + QKV (32 rows/block, 256 threads — R3 config, best measured) ----
// LDS (25600 B): Lo [0,12288) staging | stats [12288,13312) | Ap [13312,25600)
__global__ __launch_bounds__(256, 4)
void wo_qkv(const unsigned short* __restrict__ Ho,
            const unsigned short* __restrict__ WOs, const float* __restrict__ BO,
            unsigned short* __restrict__ Xres,
            const float* __restrict__ lng, const float* __restrict__ lnb,
            const unsigned short* __restrict__ QKVs, const float* __restrict__ bqkv,
            unsigned short* __restrict__ Qb, unsigned short* __restrict__ Kb,
            unsigned short* __restrict__ Vb) {
    __shared__ __align__(16) unsigned char lds[25600];
    unsigned char* Lo = lds;
    float* lsum = (float*)(lds + 12288);     // [32][4]
    float* lsq  = lsum + 128;
    unsigned char* Ap = lds + 13312;
    const int tid = threadIdx.x;
    const int lane = tid & 63;
    const int w = tid >> 6;                  // 0..3
    const int m0 = blockIdx.x * 32;
    const int q = lane >> 4, q8 = q << 3, r15 = lane & 15;
    const int nb = w * 48 + r15;

    #pragma unroll
    for (int it = 0; it < 3; ++it) {
        int c = it * 4 + w;                  // 0..11
        int g = c / 6, sk = c - g * 6;
        async_lds16(Ho + (size_t)(m0 + g * 16 + r15) * 192 + sk * 32 + q8, Lo + c * 1024);
    }
    __syncthreads();

    float4v acc[2][3];
    #pragma unroll
    for (int i = 0; i < 2; ++i)
        #pragma unroll
        for (int j = 0; j < 3; ++j)
            acc[i][j] = (float4v){0.f, 0.f, 0.f, 0.f};
    #pragma unroll
    for (int kk = 0; kk < 6; ++kk) {
        short8 af[2], wf[3];
        #pragma unroll
        for (int j = 0; j < 3; ++j)
            wf[j] = *(const short8*)(WOs + (((size_t)(w * 3 + j) * 6 + kk) << 9) + lane * 8);
        #pragma unroll
        for (int i = 0; i < 2; ++i)
            af[i] = *(const short8*)(Lo + ((i * 6 + kk) << 10) + lane * 16);
        #pragma unroll
        for (int i = 0; i < 2; ++i)
            #pragma unroll
            for (int j = 0; j < 3; ++j)
                acc[i][j] = __builtin_amdgcn_mfma_f32_16x16x32_bf16(af[i], wf[j], acc[i][j], 0, 0, 0);
    }

    // residual (vector 8B read-modify-write, fragment-major X), LN stats
    #pragma unroll
    for (int j = 0; j < 3; ++j) {
        int n = nb + j * 16;
        float bv = BO[n];
        #pragma unroll
        for (int i = 0; i < 2; ++i) {
            unsigned short* xp = Xres + XF(blockIdx.x * 2 + i, n) + q * 4;
            uintx2 u = *(const uintx2*)xp;
            float f[4]; xf_unpack(u, f);
            #pragma unroll
            for (int r = 0; r < 4; ++r) acc[i][j][r] += bv + f[r];
            uintx2 o;
            o[0] = cvt_pk_bf16(acc[i][j][0], acc[i][j][1]);
            o[1] = cvt_pk_bf16(acc[i][j][2], acc[i][j][3]);
            *(uintx2*)xp = o;
        }
    }
    #pragma unroll
    for (int i = 0; i < 2; ++i)
        #pragma unroll
        for (int r = 0; r < 4; ++r) {
            float s1 = acc[i][0][r] + acc[i][1][r] + acc[i][2][r];
            float s2 = acc[i][0][r] * acc[i][0][r] + acc[i][1][r] * acc[i][1][r] + acc[i][2][r] * acc[i][2][r];
            #pragma unroll
            for (int off = 1; off < 16; off <<= 1) {
                s1 += __shfl_xor(s1, off, 64);
                s2 += __shfl_xor(s2, off, 64);
            }
            if (r15 == 0) {
                int rl = i * 16 + q * 4 + r;
                lsum[rl * 4 + w] = s1;
                lsq[rl * 4 + w] = s2;
            }
        }
    __syncthreads();
    #pragma unroll
    for (int i = 0; i < 2; ++i) {
        float mean[4], rstd[4];
        #pragma unroll
        for (int r = 0; r < 4; ++r) {
            int rl4 = (i * 16 + q * 4 + r) * 4;
            float s  = lsum[rl4] + lsum[rl4 + 1] + lsum[rl4 + 2] + lsum[rl4 + 3];
            float ss = lsq[rl4] + lsq[rl4 + 1] + lsq[rl4 + 2] + lsq[rl4 + 3];
            float m = s * (1.0f / 192.0f);
            mean[r] = m;
            rstd[r] = rsqrtf(ss * (1.0f / 192.0f) - m * m + 1e-5f);
        }
        #pragma unroll
        for (int j = 0; j < 3; ++j) {
            int h = nb + j * 16;
            float gg = lng[h], bb = lnb[h];
            unsigned short* ap = (unsigned short*)Ap + (i * 6 + (h >> 5)) * 512
                               + ((h >> 3) & 3) * 128 + (h & 7) + q * 32;
            float v0 = (acc[i][j][0] - mean[0]) * rstd[0] * gg + bb;
            float v1 = (acc[i][j][1] - mean[1]) * rstd[1] * gg + bb;
            float v2 = (acc[i][j][2] - mean[2]) * rstd[2] * gg + bb;
            float v3 = (acc[i][j][3] - mean[3]) * rstd[3] * gg + bb;
            st2u(ap, ap + 8, v0, v1);
            st2u(ap + 16, ap + 24, v2, v3);
        }
    }
    __syncthreads();

    // QKV: 3 segments, direct global stores
    for (int seg = 0; seg < 3; ++seg) {
        float4v a2[2][3];
        #pragma unroll
        for (int i = 0; i < 2; ++i)
            #pragma unroll
            for (int j = 0; j < 3; ++j)
                a2[i][j] = (float4v){0.f, 0.f, 0.f, 0.f};
        #pragma unroll
        for (int kk = 0; kk < 6; ++kk) {
            short8 af[2], wf[3];
            #pragma unroll
            for (int j = 0; j < 3; ++j)
                wf[j] = *(const short8*)(QKVs + (((size_t)(seg * 12 + w * 3 + j) * 6 + kk) << 9) + lane * 8);
            #pragma unroll
            for (int i = 0; i < 2; ++i)
                af[i] = *(const short8*)(Ap + ((i * 6 + kk) << 10) + lane * 16);
            #pragma unroll
            for (int i = 0; i < 2; ++i)
                #pragma unroll
                for (int j = 0; j < 3; ++j)
                    a2[i][j] = __builtin_amdgcn_mfma_f32_16x16x32_bf16(af[i], wf[j], a2[i][j], 0, 0, 0);
        }
        unsigned short* dst = (seg == 0) ? Qb : (seg == 1) ? Kb : Vb;
        #pragma unroll
        for (int j = 0; j < 3; ++j) {
            int n = nb + j * 16;
            float bv = bqkv[seg * 192 + n];
            #pragma unroll
            for (int i = 0; i < 2; ++i) {
                int mrow = m0 + i * 16 + q * 4;
                #pragma unroll
                for (int r = 0; r < 4; ++r) {
                    float x = a2[i][j][r] + bv;
                    if (seg < 2) x = (x > 0.f) ? x + 1.f : __expf(x);
                    if (seg == 0) x *= 0.14433756729740643f;
                    dst[(size_t)(mrow + r) * 192 + n] = f2b(x);
                }
            }
        }
    }
}

// ---- WO + residual(reg) + LN + FFN + residual + LN + next-QKV (64 rows/block) ----
// 64 rows/wave halves L2 weight traffic (measured R6: FETCH 24.2->16.3 MB).
// LDS (51200 B): Lo [0,24576) staging/hidden | stats [24576,26624) | Ap [26624,51200)
template<bool LASTB>
__global__ __launch_bounds__(256, 2)
void wo_ffn_qkv(const unsigned short* __restrict__ Ho,
                const unsigned short* __restrict__ WOs, const float* __restrict__ BO,
                unsigned short* __restrict__ Xres,
                const float* __restrict__ ln1g, const float* __restrict__ ln1b,
                const unsigned short* __restrict__ W1s, const float* __restrict__ B1,
                const unsigned short* __restrict__ W2s, const float* __restrict__ B2,
                const float* __restrict__ ln2g, const float* __restrict__ ln2b,
                const unsigned short* __restrict__ QKVs, const float* __restrict__ bqkv,
                unsigned short* __restrict__ Qb, unsigned short* __restrict__ Kb,
                unsigned short* __restrict__ Vb) {
    __shared__ __align__(16) unsigned char lds[51200];
    unsigned char* Lo = lds;                 // staging, then FFN hidden
    float* lsum = (float*)(lds + 24576);     // [64][4]
    float* lsq  = lsum + 256;
    unsigned char* Ap = lds + 26624;
    const int tid = threadIdx.x;
    const int lane = tid & 63;
    const int w = tid >> 6;                  // 0..3
    const int m0 = blockIdx.x * 64;
    const int q = lane >> 4, q8 = q << 3, r15 = lane & 15;
    const int nb = w * 48 + r15;

    #pragma unroll
    for (int it = 0; it < 6; ++it) {
        int c = it * 4 + w;                  // 0..23
        int g = c / 6, sk = c - g * 6;
        async_lds16(Ho + (size_t)(m0 + g * 16 + r15) * 192 + sk * 32 + q8, Lo + c * 1024);
    }
    __syncthreads();

    float4v xres[4][3];
    #pragma unroll
    for (int i = 0; i < 4; ++i)
        #pragma unroll
        for (int j = 0; j < 3; ++j)
            xres[i][j] = (float4v){0.f, 0.f, 0.f, 0.f};
    #pragma unroll
    for (int kk = 0; kk < 6; ++kk) {
        short8 af[4], wf[3];
        #pragma unroll
        for (int j = 0; j < 3; ++j)
            wf[j] = *(const short8*)(WOs + (((size_t)(w * 3 + j) * 6 + kk) << 9) + lane * 8);
        #pragma unroll
        for (int i = 0; i < 4; ++i)
            af[i] = *(const short8*)(Lo + ((i * 6 + kk) << 10) + lane * 16);
        #pragma unroll
        for (int i = 0; i < 4; ++i)
            #pragma unroll
            for (int j = 0; j < 3; ++j)
                xres[i][j] = __builtin_amdgcn_mfma_f32_16x16x32_bf16(af[i], wf[j], xres[i][j], 0, 0, 0);
    }
    // residual into registers (vector 8B read; write deferred to after FFN)
    #pragma unroll
    for (int j = 0; j < 3; ++j) {
        int n = nb + j * 16;
        float bv = BO[n];
        #pragma unroll
        for (int i = 0; i < 4; ++i) {
            const unsigned short* xp = Xres + XF(blockIdx.x * 4 + i, n) + q * 4;
            uintx2 u = *(const uintx2*)xp;
            float f[4]; xf_unpack(u, f);
            #pragma unroll
            for (int r = 0; r < 4; ++r) xres[i][j][r] += bv + f[r];
        }
    }
    // LN1 stats + scatter A'
    #pragma unroll
    for (int i = 0; i < 4; ++i)
        #pragma unroll
        for (int r = 0; r < 4; ++r) {
            float s1 = xres[i][0][r] + xres[i][1][r] + xres[i][2][r];
            float s2 = xres[i][0][r] * xres[i][0][r] + xres[i][1][r] * xres[i][1][r] + xres[i][2][r] * xres[i][2][r];
            #pragma unroll
            for (int off = 1; off < 16; off <<= 1) {
                s1 += __shfl_xor(s1, off, 64);
                s2 += __shfl_xor(s2, off, 64);
            }
            if (r15 == 0) {
                int rl = i * 16 + q * 4 + r;
                lsum[rl * 4 + w] = s1;
                lsq[rl * 4 + w] = s2;
            }
        }
    __syncthreads();
    #pragma unroll
    for (int i = 0; i < 4; ++i) {
        float mean[4], rstd[4];
        #pragma unroll
        for (int r = 0; r < 4; ++r) {
            int rl4 = (i * 16 + q * 4 + r) * 4;
            float s  = lsum[rl4] + lsum[rl4 + 1] + lsum[rl4 + 2] + lsum[rl4 + 3];
            float ss = lsq[rl4] + lsq[rl4 + 1] + lsq[rl4 + 2] + lsq[rl4 + 3];
            float m = s * (1.0f / 192.0f);
            mean[r] = m;
            rstd[r] = rsqrtf(ss * (1.0f / 192.0f) - m * m + 1e-5f);
        }
        #pragma unroll
        for (int j = 0; j < 3; ++j) {
            int h = nb + j * 16;
            float gg = ln1g[h], bb = ln1b[h];
            unsigned short* ap = (unsigned short*)Ap + (i * 6 + (h >> 5)) * 512
                               + ((h >> 3) & 3) * 128 + (h & 7) + q * 32;
            float v0 = (xres[i][j][0] - mean[0]) * rstd[0] * gg + bb;
            float v1 = (xres[i][j][1] - mean[1]) * rstd[1] * gg + bb;
            float v2 = (xres[i][j][2] - mean[2]) * rstd[2] * gg + bb;
            float v3 = (xres[i][j][3] - mean[3]) * rstd[3] * gg + bb;
            st2u(ap, ap + 8, v0, v1);
            st2u(ap + 16, ap + 24, v2, v3);
        }
    }
    __syncthreads();

    // FFN: hidden chunks of 192, hidden lives only in LDS (Lo)
    float4v acc2[4][3];
    #pragma unroll
    for (int i = 0; i < 4; ++i)
        #pragma unroll
        for (int j = 0; j < 3; ++j)
            acc2[i][j] = (float4v){0.f, 0.f, 0.f, 0.f};
    for (int hc = 0; hc < 4; ++hc) {
        float4v acc1[4][3];
        #pragma unroll
        for (int i = 0; i < 4; ++i)
            #pragma unroll
            for (int j = 0; j < 3; ++j)
                acc1[i][j] = (float4v){0.f, 0.f, 0.f, 0.f};
        #pragma unroll
        for (int kk = 0; kk < 6; ++kk) {
            short8 af[4], wf[3];
            #pragma unroll
            for (int j = 0; j < 3; ++j)
                wf[j] = *(const short8*)(W1s + (((size_t)(hc * 12 + w * 3 + j) * 6 + kk) << 9) + lane * 8);
            #pragma unroll
            for (int i = 0; i < 4; ++i)
                af[i] = *(const short8*)(Ap + ((i * 6 + kk) << 10) + lane * 16);
            #pragma unroll
            for (int i = 0; i < 4; ++i)
                #pragma unroll
                for (int j = 0; j < 3; ++j)
                    acc1[i][j] = __builtin_amdgcn_mfma_f32_16x16x32_bf16(af[i], wf[j], acc1[i][j], 0, 0, 0);
        }
        __syncthreads();
        #pragma unroll
        for (int i = 0; i < 4; ++i)
            #pragma unroll
            for (int j = 0; j < 3; ++j) {
                int h = nb + j * 16;
                float bv = B1[hc * 192 + h];
                unsigned short* lp = (unsigned short*)Lo + (i * 6 + (h >> 5)) * 512
                                   + ((h >> 3) & 3) * 128 + (h & 7) + q * 32;
                float v0 = gelu_f(acc1[i][j][0] + bv);
                float v1 = gelu_f(acc1[i][j][1] + bv);
                float v2 = gelu_f(acc1[i][j][2] + bv);
                float v3 = gelu_f(acc1[i][j][3] + bv);
                st2u(lp, lp + 8, v0, v1);
                st2u(lp + 16, lp + 24, v2, v3);
            }
        __syncthreads();
        #pragma unroll
        for (int kk = 0; kk < 6; ++kk) {
            short8 af[4], wf[3];
            #pragma unroll
            for (int j = 0; j < 3; ++j)
                wf[j] = *(const short8*)(W2s + (((size_t)(w * 3 + j) * 24 + hc * 6 + kk) << 9) + lane * 8);
            #pragma unroll
            for (int i = 0; i < 4; ++i)
                af[i] = *(const short8*)(Lo + ((i * 6 + kk) << 10) + lane * 16);
            #pragma unroll
            for (int i = 0; i < 4; ++i)
                #pragma unroll
                for (int j = 0; j < 3; ++j)
                    acc2[i][j] = __builtin_amdgcn_mfma_f32_16x16x32_bf16(af[i], wf[j], acc2[i][j], 0, 0, 0);
        }
    }

    // FFN residual; single vector X write (packed bf16)
    #pragma unroll
    for (int j = 0; j < 3; ++j) {
        int n = nb + j * 16;
        float bv = B2[n];
        #pragma unroll
        for (int i = 0; i < 4; ++i) {
            #pragma unroll
            for (int r = 0; r < 4; ++r)
                xres[i][j][r] += acc2[i][j][r] + bv;
            unsigned short* xp = Xres + XF(blockIdx.x * 4 + i, n) + q * 4;
            uintx2 o;
            o[0] = cvt_pk_bf16(xres[i][j][0], xres[i][j][1]);
            o[1] = cvt_pk_bf16(xres[i][j][2], xres[i][j][3]);
            *(uintx2*)xp = o;
        }
    }
    if (LASTB) return;

    // LN2 + next-block QKV
    #pragma unroll
    for (int i = 0; i < 4; ++i)
        #pragma unroll
        for (int r = 0; r < 4; ++r) {
            float s1 = xres[i][0][r] + xres[i][1][r] + xres[i][2][r];
            float s2 = xres[i][0][r] * xres[i][0][r] + xres[i][1][r] * xres[i][1][r] + xres[i][2][r] * xres[i][2][r];
            #pragma unroll
            for (int off = 1; off < 16; off <<= 1) {
                s1 += __shfl_xor(s1, off, 64);
                s2 += __shfl_xor(s2, off, 64);
            }
            if (r15 == 0) {
                int rl = i * 16 + q * 4 + r;
                lsum[rl * 4 + w] = s1;
                lsq[rl * 4 + w] = s2;
            }
        }
    __syncthreads();
    #pragma unroll
    for (int i = 0; i < 4; ++i) {
        float mean[4], rstd[4];
        #pragma unroll
        for (int r = 0; r < 4; ++r) {
            int rl4 = (i * 16 + q * 4 + r) * 4;
            float s  = lsum[rl4] + lsum[rl4 + 1] + lsum[rl4 + 2] + lsum[rl4 + 3];
            float ss = lsq[rl4] + lsq[rl4 + 1] + lsq[rl4 + 2] + lsq[rl4 + 3];
            float m = s * (1.0f / 192.0f);
            mean[r] = m;
            rstd[r] = rsqrtf(ss * (1.0f / 192.0f) - m * m + 1e-5f);
        }
        #pragma unroll
        for (int j = 0; j < 3; ++j) {
            int h = nb + j * 16;
            float gg = ln2g[h], bb = ln2b[h];
            unsigned short* ap = (unsigned short*)Ap + (i * 6 + (h >> 5)) * 512
                               + ((h >> 3) & 3) * 128 + (h & 7) + q * 32;
            float v0 = (xres[i][j][0] - mean[0]) * rstd[0] * gg + bb;
            float v1 = (xres[i][j][1] - mean[1]) * rstd[1] * gg + bb;
            float v2 = (xres[i][j][2] - mean[2]) * rstd[2] * gg + bb;
            float v3 = (xres[i][j][3] - mean[3]) * rstd[3] * gg + bb;
            st2u(ap, ap + 8, v0, v1);
            st2u(ap + 16, ap + 24, v2, v3);
        }
    }
    __syncthreads();

    // next-block QKV: direct global stores
    for (int seg = 0; seg < 3; ++seg) {
        float4v a2[4][3];
        #pragma unroll
        for (int i = 0; i < 4; ++i)
            #pragma unroll
            for (int j = 0; j < 3; ++j)
                a2[i][j] = (float4v){0.f, 0.f, 0.f, 0.f};
        #pragma unroll
        for (int kk = 0; kk < 6; ++kk) {
            short8 af[4], wf[3];
            #pragma unroll
            for (int j = 0; j < 3; ++j)
                wf[j] = *(const short8*)(QKVs + (((size_t)(seg * 12 + w * 3 + j) * 6 + kk) << 9) + lane * 8);
            #pragma unroll
            for (int i = 0; i < 4; ++i)
                af[i] = *(const short8*)(Ap + ((i * 6 + kk) << 10) + lane * 16);
            #pragma unroll
            for (int i = 0; i < 4; ++i)
                #pragma unroll
                for (int j = 0; j < 3; ++j)
                    a2[i][j] = __builtin_amdgcn_mfma_f32_16x16x32_bf16(af[i], wf[j], a2[i][j], 0, 0, 0);
        }
        unsigned short* dst = (seg == 0) ? Qb : (seg == 1) ? Kb : Vb;
        #pragma unroll
        for (int j = 0; j < 3; ++j) {
            int n = nb + j * 16;
            float bv = bqkv[seg * 192 + n];
            #pragma unroll
            for (int i = 0; i < 4; ++i) {
                int mrow = m0 + i * 16 + q * 4;
                #pragma unroll
                for (int r = 0; r < 4; ++r) {
                    float x = a2[i][j][r] + bv;
                    if (seg < 2) x = (x > 0.f) ? x + 1.f : __expf(x);
                    if (seg == 0) x *= 0.14433756729740643f;
                    dst[(size_t)(mrow + r) * 192 + n] = f2b(x);
                }
            }
        }
    }
}

// ---------------- ROW attention: one block per (row-group, head) ----------------
__global__ __launch_bounds__(256) void attn_rowh(const unsigned short* __restrict__ Qb,
                                                 const unsigned short* __restrict__ Kb,
                                                 const unsigned short* __restrict__ Vb,
                                                 unsigned short* __restrict__ O) {
    __shared__ __align__(16) unsigned char lds[58368];
    unsigned char* stg = lds;                              // [256 rows][208 B] K|V swizzled
    float* pub = (float*)lds;                              // [4][48][64] f32 (aliases stg)
    unsigned short* kvs = (unsigned short*)(lds + 49152);  // [64][72] shorts
    const int tid = threadIdx.x;
    const int lane = tid & 63;
    const int wq = tid >> 6;                 // ks quarter 0..3
    const int h = blockIdx.x & 3;
    const size_t base = (size_t)(blockIdx.x >> 2) * 256;
    const int q = lane >> 4, r15 = lane & 15, q8 = q * 8;

    // stage: 256 rows x (48K + 48V) shorts, row stride 208B, XOR ((row>>3)&3)<<5
    short8 rg[12];
    #pragma unroll
    for (int it = 0; it < 12; ++it) {
        int u = it * 256 + tid;
        int row = u / 12, c8 = u - (u / 12) * 12;
        const unsigned short* gp = (c8 < 6)
            ? (Kb + (base + row) * 192 + h * 48 + c8 * 8)
            : (Vb + (base + row) * 192 + h * 48 + (c8 - 6) * 8);
        rg[it] = *(const short8*)gp;
    }
    #pragma unroll
    for (int it = 0; it < 12; ++it) {
        int u = it * 256 + tid;
        int row = u / 12, c8 = u - (u / 12) * 12;
        int ba = (row * 208 + c8 * 16) ^ (((row >> 3) & 3) << 5);
        *(short8*)(stg + ba) = rg[it];
    }
    __syncthreads();

    short8 onesf;
    #pragma unroll
    for (int e = 0; e < 8; ++e) onesf[e] = (short)0x3F80;

    float4v kv[3][4];
    #pragma unroll
    for (int i = 0; i < 3; ++i)
        #pragma unroll
        for (int j = 0; j < 4; ++j)
            kv[i][j] = (float4v){0.f, 0.f, 0.f, 0.f};

    #pragma unroll
    for (int sc = 0; sc < 2; ++sc) {
        int ks0 = wq * 64 + sc * 32;
        short8 af[3], bf[3];
        #pragma unroll
        for (int t = 0; t < 3; ++t) {
            #pragma unroll
            for (int j = 0; j < 8; ++j) {
                int row = ks0 + q8 + j;
                int sw = ((row >> 3) & 3) << 5;
                af[t][j] = *(const short*)(stg + ((row * 208 + (t * 16 + r15) * 2) ^ sw));
                bf[t][j] = *(const short*)(stg + ((row * 208 + 96 + (t * 16 + r15) * 2) ^ sw));
            }
        }
        #pragma unroll
        for (int i = 0; i < 3; ++i) {
            #pragma unroll
            for (int j = 0; j < 3; ++j)
                kv[i][j] = __builtin_amdgcn_mfma_f32_16x16x32_bf16(af[i], bf[j], kv[i][j], 0, 0, 0);
            kv[i][3] = __builtin_amdgcn_mfma_f32_16x16x32_bf16(af[i], onesf, kv[i][3], 0, 0, 0);
        }
    }
    __syncthreads();                         // staging reads done; pub/kvs may reuse space

    // publish partial KV states (f32)
    {
        float* kp = pub + wq * 3072;
        #pragma unroll
        for (int i = 0; i < 3; ++i)
            #pragma unroll
            for (int j = 0; j < 4; ++j)
                #pragma unroll
                for (int r = 0; r < 4; ++r)
                    kp[((i * 4 + j) * 4 + r) * 64 + lane] = kv[i][j][r];
    }
    __syncthreads();

    // zero kvs cols 48..63 (k_ch beyond 47 must be 0 for kk=1 fragments)
    {
        unsigned int* kz = (unsigned int*)kvs;
        #pragma unroll
        for (int z = 0; z < 2; ++z) {
            int zz = z * 256 + tid;
            int zr = zz >> 3, zc = zz & 7;
            kz[zr * 36 + 24 + zc] = 0;
        }
    }
    // combine: wave wq sums V-block j==wq across 4 partials, emits kvs rows
    #pragma unroll
    for (int i = 0; i < 3; ++i)
        #pragma unroll
        for (int r = 0; r < 4; ++r) {
            int idx = ((i * 4 + wq) * 4 + r) * 64 + lane;
            float s = pub[idx] + pub[3072 + idx] + pub[6144 + idx] + pub[9216 + idx];
            int kc = i * 16 + q * 4 + r;
            if (wq < 3)
                kvs[(wq * 16 + r15) * 72 + kc] = f2b(s);
            else
                kvs[(48 + r15) * 72 + kc] = (r15 == 0) ? f2b(s) : (unsigned short)0;
        }
    __syncthreads();

    short8 bkv[2][4];
    #pragma unroll
    for (int kk = 0; kk < 2; ++kk)
        #pragma unroll
        for (int t = 0; t < 4; ++t)
            bkv[kk][t] = *(const short8*)&kvs[(t * 16 + r15) * 72 + kk * 32 + q8];

    #pragma unroll
    for (int m = 0; m < 4; ++m) {
        int mt = wq * 4 + m;
        float4v o[4];
        #pragma unroll
        for (int t = 0; t < 4; ++t) o[t] = (float4v){0.f, 0.f, 0.f, 0.f};
        #pragma unroll
        for (int kk = 0; kk < 2; ++kk) {
            const unsigned short* qp = Qb + (base + (size_t)(mt * 16 + r15)) * 192
                                       + h * 48 + kk * 32 + q8;
            short8 aq = *(const short8*)qp;
            #pragma unroll
            for (int t = 0; t < 4; ++t)
                o[t] = __builtin_amdgcn_mfma_f32_16x16x32_bf16(aq, bkv[kk][t], o[t], 0, 0, 0);
        }
        #pragma unroll
        for (int r = 0; r < 4; ++r) {
            float den = __shfl(o[3][r], q << 4);
            float z = 1.0f / (den + 1e-6f);
            int n = mt * 16 + q * 4 + r;
            unsigned short* op = O + (base + (size_t)n) * 192 + h * 48;
            #pragma unroll
            for (int t = 0; t < 3; ++t)
                op[t * 16 + r15] = f2b(o[t][r] * z);
        }
    }
}

// ---------------- COL attention (pixel-major K/V, swizzled LDS gather) ----------------
template<int N, int MSTR>
__global__ __launch_bounds__(256) void attn_axial(const unsigned short* __restrict__ Qb,
                                                  const unsigned short* __restrict__ Kb,
                                                  const unsigned short* __restrict__ Vb,
                                                  unsigned short* __restrict__ O) {
    __shared__ unsigned short KV[32][400];
    __shared__ unsigned short kvs[4][64][72];
    unsigned char* kvb = (unsigned char*)KV;
    const int tid = threadIdx.x;
    const int lane = tid & 63;
    const int w = tid >> 6;
    const int q = lane >> 4, r15 = lane & 15, q8 = q * 8;
    size_t base;
    if (MSTR == 1) base = (size_t)blockIdx.x * N;
    else           base = (size_t)(blockIdx.x >> 8) * 16384 + (blockIdx.x & 255);

    unsigned int* kz = (unsigned int*)&kvs[w][0][0];
    #pragma unroll
    for (int ii = 0; ii < 36; ++ii) kz[lane + ii * 64] = 0;

    short8 onesf;
    #pragma unroll
    for (int e = 0; e < 8; ++e) onesf[e] = (short)0x3F80;

    float4v kv[3][4];
    #pragma unroll
    for (int i = 0; i < 3; ++i)
        #pragma unroll
        for (int j = 0; j < 4; ++j)
            kv[i][j] = (float4v){0.f, 0.f, 0.f, 0.f};

    for (int ks = 0; ks < N; ks += 32) {
        #pragma unroll
        for (int it = 0; it < 6; ++it) {
            int cc = tid + it * 256;
            int row = cc / 48, c8 = cc - (cc / 48) * 48;
            size_t poff = (base + (size_t)(ks + row) * MSTR) * 192;
            const unsigned short* gp = (c8 < 24) ? (Kb + poff + c8 * 8) : (Vb + poff + (c8 - 24) * 8);
            int ba = (row * 800 + c8 * 16) ^ (((row >> 3) & 3) << 5);
            *(short8*)(kvb + ba) = *(const short8*)gp;
        }
        __syncthreads();
        short8 af[3], bf[3];
        #pragma unroll
        for (int t = 0; t < 3; ++t) {
            #pragma unroll
            for (int j = 0; j < 8; ++j) {
                int row = q8 + j;
                int sw = ((row >> 3) & 3) << 5;
                af[t][j] = *(short*)(kvb + ((row * 800 + (w * 48 + t * 16 + r15) * 2) ^ sw));
                bf[t][j] = *(short*)(kvb + ((row * 800 + 384 + (w * 48 + t * 16 + r15) * 2) ^ sw));
            }
        }
        #pragma unroll
        for (int i = 0; i < 3; ++i) {
            #pragma unroll
            for (int j = 0; j < 3; ++j)
                kv[i][j] = __builtin_amdgcn_mfma_f32_16x16x32_bf16(af[i], bf[j], kv[i][j], 0, 0, 0);
            kv[i][3] = __builtin_amdgcn_mfma_f32_16x16x32_bf16(af[i], onesf, kv[i][3], 0, 0, 0);
        }
        __syncthreads();
    }

    #pragma unroll
    for (int i = 0; i < 3; ++i) {
        #pragma unroll
        for (int j = 0; j < 3; ++j)
            #pragma unroll
            for (int r = 0; r < 4; ++r)
                kvs[w][j * 16 + r15][i * 16 + q * 4 + r] = f2b(kv[i][j][r]);
        if (r15 == 0)
            #pragma unroll
            for (int r = 0; r < 4; ++r)
                kvs[w][48][i * 16 + q * 4 + r] = f2b(kv[i][3][r]);
    }

    short8 bkv[2][4];
    #pragma unroll
    for (int kk = 0; kk < 2; ++kk)
        #pragma unroll
        for (int t = 0; t < 4; ++t)
            bkv[kk][t] = *(const short8*)&kvs[w][t * 16 + r15][kk * 32 + q8];

    for (int mt = 0; mt < N / 16; ++mt) {
        float4v o[4];
        #pragma unroll
        for (int t = 0; t < 4; ++t) o[t] = (float4v){0.f, 0.f, 0.f, 0.f};
        #pragma unroll
        for (int kk = 0; kk < 2; ++kk) {
            const unsigned short* qp = Qb + (base + (size_t)(mt * 16 + r15) * MSTR) * 192
                                       + w * 48 + kk * 32 + q8;
            short8 aq = *(const short8*)qp;
            #pragma unroll
            for (int t = 0; t < 4; ++t)
                o[t] = __builtin_amdgcn_mfma_f32_16x16x32_bf16(aq, bkv[kk][t], o[t], 0, 0, 0);
        }
        #pragma unroll
        for (int r = 0; r < 4; ++r) {
            float den = __shfl(o[3][r], q << 4);
            float z = 1.0f / (den + 1e-6f);
            int n = mt * 16 + q * 4 + r;
            unsigned short* op = O + (base + (size_t)n * MSTR) * 192 + w * 48;
            #pragma unroll
            for (int t = 0; t < 3; ++t)
                op[t * 16 + r15] = f2b(o[t][r] * z);
        }
    }
}

__global__ __launch_bounds__(256) void final_kernel(const unsigned short* __restrict__ X,
                                                    const float* __restrict__ pw_w,
                                                    const float* __restrict__ pw_b, float* __restrict__ out) {
    int wave = threadIdx.x >> 6;
    int lane = threadIdx.x & 63;
    int p = blockIdx.x * 4 + wave;
    const unsigned short* xp = X + XF(p >> 4, 0) + (p & 15);
    float s = b2f(xp[(size_t)lane << 4]) * pw_w[lane]
            + b2f(xp[(size_t)(lane + 64) << 4]) * pw_w[lane + 64]
            + b2f(xp[(size_t)(lane + 128) << 4]) * pw_w[lane + 128];
    #pragma unroll
    for (int off = 32; off; off >>= 1) s += __shfl_xor(s, off, 64);
    if (lane == 0) {
        float o = s + pw_b[0];
        float e = expf(o);
        out[p] = 1.0f - 1.0f / (2.0f + e);
    }
}

extern "C" void kernel_launch(void* const* d_in, const int* in_sizes, int n_in,
                              void* d_out, int out_size, void* d_ws, size_t ws_size,
                              hipStream_t stream) {
    const int*   tokens = (const int*)  d_in[0];
    const float* emb    = (const float*)d_in[1];
    const float* proj_w = (const float*)d_in[2];
    const float* proj_b = (const float*)d_in[3];
    const float* ln_g   = (const float*)d_in[4];
    const float* ln_b   = (const float*)d_in[5];
    const float* wq     = (const float*)d_in[6];
    const float* wk     = (const float*)d_in[7];
    const float* wv     = (const float*)d_in[8];
    const float* wo     = (const float*)d_in[9];
    const float* bq     = (const float*)d_in[10];
    const float* bk     = (const float*)d_in[11];
    const float* bv     = (const float*)d_in[12];
    const float* bo     = (const float*)d_in[13];
    const float* ffn_w1 = (const float*)d_in[14];
    const float* ffn_b1 = (const float*)d_in[15];
    const float* ffn_w2 = (const float*)d_in[16];
    const float* ffn_b2 = (const float*)d_in[17];
    const float* pw_w   = (const float*)d_in[18];
    const float* pw_b   = (const float*)d_in[19];

    unsigned short* X    = (unsigned short*)d_ws;        // bf16 residual stream (fragment-major)
    unsigned short* Ho   = X + BUF;
    unsigned short* Qb   = Ho + BUF;
    unsigned short* Kb   = Qb + BUF;
    unsigned short* Vb   = Kb + BUF;
    unsigned short* Eg   = Vb + BUF;                     // NP*64
    unsigned short* wqkvb = Eg + (size_t)NP * 64;
    const int QKVSZ = NBLK * 2 * 576 * CCH;
    const int WSZ   = NBLK * 2 * CCH * CCH;
    const int FSZ   = NBLK * 768 * CCH;
    unsigned short* wob = wqkvb + QKVSZ;
    unsigned short* w1b = wob + WSZ;
    unsigned short* w2b = w1b + FSZ;
    unsigned short* pjb = w2b + FSZ;                     // 12288
    float* bqkvb = (float*)(pjb + 12288 + 32);
    float* Xt = (float*)Qb;                              // proj tmp fp32 (spans Qb+Kb, free pre-loop)

    // fused prep: all weight swizzles + bias concat + embedding gather in one launch
    prep_all<<<SEG_G / 256, 256, 0, stream>>>(wq, wk, wv, wo, ffn_w1, ffn_w2, proj_w,
                                              bq, bk, bv, tokens, emb,
                                              wqkvb, wob, w1b, w2b, pjb, bqkvb, Eg);

    mm192<64, 1><<<dim3(1, NP / 64), 256, 0, stream>>>(Eg, pjb, proj_b,
                                                       nullptr, nullptr, nullptr, Xt, NP, CCH, 64);
    rotary_ln_kernel<<<NP / 4, 256, 0, stream>>>(Xt, X, Ho, ln_g, ln_b);
    mm192<128, 0><<<dim3(3, NP / 128), 256, 0, stream>>>(Ho, wqkvb, bqkvb,
                                                         Qb, Kb, Vb, nullptr, NP, 576, CCH);

    for (int i = 0; i < NBLK; ++i) {
        size_t wi0 = (size_t)(i * 2), wi1 = wi0 + 1;
        attn_rowh<<<BB * SS * 4, 256, 0, stream>>>(Qb, Kb, Vb, Ho);
        wo_qkv<<<NP / 32, 256, 0, stream>>>(Ho, wob + wi0 * CCH * CCH, bo + wi0 * CCH, X,
                                            ln_g + (size_t)(i * 3 + 1) * CCH, ln_b + (size_t)(i * 3 + 1) * CCH,
                                            wqkvb + wi1 * 576 * CCH, bqkvb + wi1 * 576, Qb, Kb, Vb);
        attn_axial<SS, LL><<<BB * LL, 256, 0, stream>>>(Qb, Kb, Vb, Ho);
        if (i < NBLK - 1) {
            size_t wn0 = (size_t)((i + 1) * 2);
            wo_ffn_qkv<false><<<NP / 64, 256, 0, stream>>>(
                Ho, wob + wi1 * CCH * CCH, bo + wi1 * CCH, X,
                ln_g + (size_t)(i * 3 + 2) * CCH, ln_b + (size_t)(i * 3 + 2) * CCH,
                w1b + (size_t)i * 768 * CCH, ffn_b1 + (size_t)i * 768,
                w2b + (size_t)i * CCH * 768, ffn_b2 + (size_t)i * CCH,
                ln_g + (size_t)((i + 1) * 3) * CCH, ln_b + (size_t)((i + 1) * 3) * CCH,
                wqkvb + wn0 * 576 * CCH, bqkvb + wn0 * 576, Qb, Kb, Vb);
        } else {
            wo_ffn_qkv<true><<<NP / 64, 256, 0, stream>>>(
                Ho, wob + wi1 * CCH * CCH, bo + wi1 * CCH, X,
                ln_g + (size_t)(i * 3 + 2) * CCH, ln_b + (size_t)(i * 3 + 2) * CCH,
                w1b + (size_t)i * 768 * CCH, ffn_b1 + (size_t)i * 768,
                w2b + (size_t)i * CCH * 768, ffn_b2 + (size_t)i * CCH,
                nullptr, nullptr, nullptr, nullptr, nullptr, nullptr, nullptr);
        }
    }
    final_kernel<<<NP / 4, 256, 0, stream>>>(X, pw_w, pw_b, (float*)d_out);
}